// Round 1
// baseline (2877.304 us; speedup 1.0000x reference)
//
#include <hip/hip_runtime.h>
#include <math.h>

#define BATCH 16
#define TSTEPS 128
#define UNITS 64
#define FEAT 512
#define FLAT 3136
#define OUTROW 576           // 512 + 64
#define OUT_FEATS (BATCH * TSTEPS * OUTROW)   // 1179648
#define MEMN 16

// ---------------- conv1: in [n,84,84,4] -> out [n,20,20,32], w[8,8,4,32], stride 4, ReLU
__global__ __launch_bounds__(256) void conv1_kernel(
    const float* __restrict__ in, const float* __restrict__ w,
    const float* __restrict__ bias, float* __restrict__ out, int n0)
{
    __shared__ float wl[8 * 8 * 4 * 32];   // 8192 floats = 32 KB
    const int tid = threadIdx.x;
    for (int i = tid; i < 8192; i += 256) wl[i] = w[i];
    __syncthreads();

    const int oc = tid & 31;
    const int ps = tid >> 5;               // 0..7
    const int img = n0 + blockIdx.x;
    const float* inb = in + (size_t)img * (84 * 84 * 4);

    float acc[50];
#pragma unroll
    for (int i = 0; i < 50; ++i) acc[i] = 0.f;

    int ibase[50];
#pragma unroll
    for (int i = 0; i < 50; ++i) {
        int px = ps + (i << 3);            // 0..399
        int y = px / 20, x = px % 20;
        ibase[i] = (y * 4 * 84 + x * 4) * 4;
    }

    for (int ky = 0; ky < 8; ++ky) {
        for (int kx = 0; kx < 8; ++kx) {
            const int koff = (ky * 84 + kx) * 4;
            const int wbase = ((ky * 8 + kx) * 4) * 32 + oc;
            const float w0 = wl[wbase];
            const float w1 = wl[wbase + 32];
            const float w2 = wl[wbase + 64];
            const float w3 = wl[wbase + 96];
#pragma unroll
            for (int i = 0; i < 50; ++i) {
                const float4 v = *reinterpret_cast<const float4*>(inb + ibase[i] + koff);
                acc[i] = fmaf(v.x, w0, acc[i]);
                acc[i] = fmaf(v.y, w1, acc[i]);
                acc[i] = fmaf(v.z, w2, acc[i]);
                acc[i] = fmaf(v.w, w3, acc[i]);
            }
        }
    }

    const float b = bias[oc];
    float* ob = out + (size_t)blockIdx.x * (400 * 32);
#pragma unroll
    for (int i = 0; i < 50; ++i) {
        int px = ps + (i << 3);
        ob[px * 32 + oc] = fmaxf(acc[i] + b, 0.f);
    }
}

// ---------------- conv2: in [n,20,20,32] -> out [n,9,9,64], w[4,4,32,64], stride 2, ReLU
__global__ __launch_bounds__(256) void conv2_kernel(
    const float* __restrict__ in, const float* __restrict__ w,
    const float* __restrict__ bias, float* __restrict__ out)
{
    __shared__ float wl[32 * 64];          // one (ky,kx) slice, 8 KB
    const int tid = threadIdx.x;
    const int oc = tid & 63;
    const int ps = tid >> 6;               // 0..3
    const int img = blockIdx.x;
    const float* inb = in + (size_t)img * (20 * 20 * 32);

    float acc[21];
#pragma unroll
    for (int i = 0; i < 21; ++i) acc[i] = 0.f;

    int ibase[21];
#pragma unroll
    for (int i = 0; i < 21; ++i) {
        int px = ps + (i << 2);
        int pc = px < 81 ? px : 80;
        int y = pc / 9, x = pc % 9;
        ibase[i] = (y * 2 * 20 + x * 2) * 32;
    }

    for (int ky = 0; ky < 4; ++ky) {
        for (int kx = 0; kx < 4; ++kx) {
            __syncthreads();
            const float* wsrc = w + (size_t)(ky * 4 + kx) * 2048;
            for (int i = tid; i < 2048; i += 256) wl[i] = wsrc[i];
            __syncthreads();
            const int koff = (ky * 20 + kx) * 32;
            for (int ic = 0; ic < 32; ic += 4) {
                const float w0 = wl[(ic + 0) * 64 + oc];
                const float w1 = wl[(ic + 1) * 64 + oc];
                const float w2 = wl[(ic + 2) * 64 + oc];
                const float w3 = wl[(ic + 3) * 64 + oc];
#pragma unroll
                for (int i = 0; i < 21; ++i) {
                    const float4 v = *reinterpret_cast<const float4*>(inb + ibase[i] + koff + ic);
                    acc[i] = fmaf(v.x, w0, acc[i]);
                    acc[i] = fmaf(v.y, w1, acc[i]);
                    acc[i] = fmaf(v.z, w2, acc[i]);
                    acc[i] = fmaf(v.w, w3, acc[i]);
                }
            }
        }
    }

    const float b = bias[oc];
    float* ob = out + (size_t)img * (81 * 64);
#pragma unroll
    for (int i = 0; i < 21; ++i) {
        int px = ps + (i << 2);
        if (px < 81) ob[px * 64 + oc] = fmaxf(acc[i] + b, 0.f);
    }
}

// ---------------- conv3: in [n,9,9,64] -> out [n,7,7,64], w[3,3,64,64], stride 1, ReLU
__global__ __launch_bounds__(256) void conv3_kernel(
    const float* __restrict__ in, const float* __restrict__ w,
    const float* __restrict__ bias, float* __restrict__ out)
{
    __shared__ float wl[64 * 64];          // one (ky,kx) slice, 16 KB
    const int tid = threadIdx.x;
    const int oc = tid & 63;
    const int ps = tid >> 6;               // 0..3
    const int img = blockIdx.x;
    const float* inb = in + (size_t)img * (9 * 9 * 64);

    float acc[13];
#pragma unroll
    for (int i = 0; i < 13; ++i) acc[i] = 0.f;

    int ibase[13];
#pragma unroll
    for (int i = 0; i < 13; ++i) {
        int px = ps + (i << 2);
        int pc = px < 49 ? px : 48;
        int y = pc / 7, x = pc % 7;
        ibase[i] = (y * 9 + x) * 64;
    }

    for (int ky = 0; ky < 3; ++ky) {
        for (int kx = 0; kx < 3; ++kx) {
            __syncthreads();
            const float* wsrc = w + (size_t)(ky * 3 + kx) * 4096;
            for (int i = tid; i < 4096; i += 256) wl[i] = wsrc[i];
            __syncthreads();
            const int koff = (ky * 9 + kx) * 64;
            for (int ic = 0; ic < 64; ic += 4) {
                const float w0 = wl[(ic + 0) * 64 + oc];
                const float w1 = wl[(ic + 1) * 64 + oc];
                const float w2 = wl[(ic + 2) * 64 + oc];
                const float w3 = wl[(ic + 3) * 64 + oc];
#pragma unroll
                for (int i = 0; i < 13; ++i) {
                    const float4 v = *reinterpret_cast<const float4*>(inb + ibase[i] + koff + ic);
                    acc[i] = fmaf(v.x, w0, acc[i]);
                    acc[i] = fmaf(v.y, w1, acc[i]);
                    acc[i] = fmaf(v.z, w2, acc[i]);
                    acc[i] = fmaf(v.w, w3, acc[i]);
                }
            }
        }
    }

    const float b = bias[oc];
    float* ob = out + (size_t)img * (49 * 64);
#pragma unroll
    for (int i = 0; i < 13; ++i) {
        int px = ps + (i << 2);
        if (px < 49) ob[px * 64 + oc] = fmaxf(acc[i] + b, 0.f);
    }
}

// ---------------- tiled fp32 GEMM: C[M,N] = act(A[M,K] @ B[K,N] + bias)
// BM=BN=64, BK=16, 256 threads, 4x4 micro-tile. M%64==0, N%64==0, K%16==0.
template <int RELU>
__global__ __launch_bounds__(256) void gemm_kernel(
    const float* __restrict__ A, int lda,
    const float* __restrict__ B, int ldb,
    const float* __restrict__ bias,
    float* __restrict__ C, int ldc,
    int M, int N, int K)
{
    __shared__ float As[64][17];
    __shared__ float Bs[16][64];

    const int tid = threadIdx.x;
    const int bm0 = blockIdx.x * 64;
    const int bn0 = blockIdx.y * 64;
    const int tx = tid & 15, ty = tid >> 4;

    const int arow = tid >> 2;
    const int acol = (tid & 3) * 4;
    const int brow = tid >> 4;
    const int bcol = (tid & 15) * 4;

    const float* Ap = A + (size_t)(bm0 + arow) * lda + acol;
    const float* Bp = B + (size_t)brow * ldb + bn0 + bcol;

    float c[4][4];
#pragma unroll
    for (int i = 0; i < 4; ++i)
#pragma unroll
        for (int j = 0; j < 4; ++j) c[i][j] = 0.f;

    for (int k0 = 0; k0 < K; k0 += 16) {
        const float4 av = *reinterpret_cast<const float4*>(Ap + k0);
        const float4 bv = *reinterpret_cast<const float4*>(Bp + (size_t)k0 * ldb);
        __syncthreads();
        As[arow][acol + 0] = av.x;
        As[arow][acol + 1] = av.y;
        As[arow][acol + 2] = av.z;
        As[arow][acol + 3] = av.w;
        *reinterpret_cast<float4*>(&Bs[brow][bcol]) = bv;
        __syncthreads();
#pragma unroll
        for (int k = 0; k < 16; ++k) {
            float a0 = As[ty * 4 + 0][k];
            float a1 = As[ty * 4 + 1][k];
            float a2 = As[ty * 4 + 2][k];
            float a3 = As[ty * 4 + 3][k];
            float b0 = Bs[k][tx * 4 + 0];
            float b1 = Bs[k][tx * 4 + 1];
            float b2 = Bs[k][tx * 4 + 2];
            float b3 = Bs[k][tx * 4 + 3];
            c[0][0] = fmaf(a0, b0, c[0][0]); c[0][1] = fmaf(a0, b1, c[0][1]);
            c[0][2] = fmaf(a0, b2, c[0][2]); c[0][3] = fmaf(a0, b3, c[0][3]);
            c[1][0] = fmaf(a1, b0, c[1][0]); c[1][1] = fmaf(a1, b1, c[1][1]);
            c[1][2] = fmaf(a1, b2, c[1][2]); c[1][3] = fmaf(a1, b3, c[1][3]);
            c[2][0] = fmaf(a2, b0, c[2][0]); c[2][1] = fmaf(a2, b1, c[2][1]);
            c[2][2] = fmaf(a2, b2, c[2][2]); c[2][3] = fmaf(a2, b3, c[2][3]);
            c[3][0] = fmaf(a3, b0, c[3][0]); c[3][1] = fmaf(a3, b1, c[3][1]);
            c[3][2] = fmaf(a3, b2, c[3][2]); c[3][3] = fmaf(a3, b3, c[3][3]);
        }
    }

#pragma unroll
    for (int i = 0; i < 4; ++i) {
        const int row = bm0 + ty * 4 + i;
#pragma unroll
        for (int j = 0; j < 4; ++j) {
            const int col = bn0 + tx * 4 + j;
            float v = c[i][j] + bias[col];
            if (RELU) v = fmaxf(v, 0.f);
            C[(size_t)row * ldc + col] = v;
        }
    }
}

// ---------------- GRU recurrence: one block (64 threads, 1 wave) per batch row
__global__ __launch_bounds__(64) void gru_kernel(
    const float* __restrict__ mx,     // [2048,192] = feats @ gru_k + bi
    const float* __restrict__ rk,     // [64,192]
    const float* __restrict__ gb,     // [2,192]; br = gb + 192
    const int*   __restrict__ dones,  // [16,128]
    const float* __restrict__ state0, // [16,64]
    const int*   __restrict__ step0,  // [16]
    float* __restrict__ out)          // full out base
{
    __shared__ float rkl[64 * 192];   // 48 KB
    const int b = blockIdx.x;
    const int u = threadIdx.x;
    for (int i = u; i < 64 * 192; i += 64) rkl[i] = rk[i];
    __syncthreads();

    float h = state0[b * 64 + u];
    int step = step0[b];
    const float brz = gb[192 + u];
    const float brr = gb[192 + 64 + u];
    const float brh = gb[192 + 128 + u];

    for (int t = 0; t < TSTEPS; ++t) {
        const int bt = b * TSTEPS + t;
        float az = 0.f, ar = 0.f, ah = 0.f;
#pragma unroll 16
        for (int j = 0; j < 64; ++j) {
            const float hj = __shfl(h, j);
            az = fmaf(hj, rkl[j * 192 + u], az);
            ar = fmaf(hj, rkl[j * 192 + 64 + u], ar);
            ah = fmaf(hj, rkl[j * 192 + 128 + u], ah);
        }
        const float xz = mx[(size_t)bt * 192 + u];
        const float xr = mx[(size_t)bt * 192 + 64 + u];
        const float xh = mx[(size_t)bt * 192 + 128 + u];
        const float z = 1.f / (1.f + __expf(-(xz + az + brz)));
        const float r = 1.f / (1.f + __expf(-(xr + ar + brr)));
        const float hh = tanhf(xh + r * (ah + brh));
        const float hn = z * h + (1.f - z) * hh;

        out[(size_t)bt * OUTROW + 512 + u] = hn;

        step += 1;
        const int reset = (dones[bt] == 1) || ((step % MEMN) == 0);
        h = reset ? 0.f : hn;
        step = reset ? 0 : step;
    }

    out[OUT_FEATS + b * 64 + u] = h;
    if (u == 0) out[OUT_FEATS + 1024 + b] = (float)step;
}

extern "C" void kernel_launch(void* const* d_in, const int* in_sizes, int n_in,
                              void* d_out, int out_size, void* d_ws, size_t ws_size,
                              hipStream_t stream) {
    const float* inputs = (const float*)d_in[0];
    const int*   dones  = (const int*)d_in[1];
    const float* state0 = (const float*)d_in[2];
    const int*   step0  = (const int*)d_in[3];
    const float* c1w = (const float*)d_in[4];
    const float* c1b = (const float*)d_in[5];
    const float* c2w = (const float*)d_in[6];
    const float* c2b = (const float*)d_in[7];
    const float* c3w = (const float*)d_in[8];
    const float* c3b = (const float*)d_in[9];
    const float* dw  = (const float*)d_in[10];
    const float* db  = (const float*)d_in[11];
    const float* gk  = (const float*)d_in[12];
    const float* grk = (const float*)d_in[13];
    const float* gbv = (const float*)d_in[14];

    float* out = (float*)d_out;
    float* ws  = (float*)d_ws;

    const int NIMG = BATCH * TSTEPS;        // 2048
    const size_t mx_floats = (size_t)NIMG * 192;

    // choose largest chunk that fits the workspace
    const int opts[6] = {2048, 1024, 512, 256, 128, 64};
    int chunk = 64;
    const size_t avail = ws_size / sizeof(float);
    for (int i = 0; i < 6; ++i) {
        size_t need = mx_floats + (size_t)opts[i] * (12800 + 5184);
        if (need <= avail) { chunk = opts[i]; break; }
    }

    float* mxbuf = ws;
    float* bufA = ws + mx_floats;                       // conv1 out, reused for conv3 out
    float* bufB = bufA + (size_t)chunk * 12800;         // conv2 out

    for (int n0 = 0; n0 < NIMG; n0 += chunk) {
        conv1_kernel<<<chunk, 256, 0, stream>>>(inputs, c1w, c1b, bufA, n0);
        conv2_kernel<<<chunk, 256, 0, stream>>>(bufA, c2w, c2b, bufB);
        conv3_kernel<<<chunk, 256, 0, stream>>>(bufB, c3w, c3b, bufA);
        dim3 g(chunk / 64, FEAT / 64);
        gemm_kernel<1><<<g, 256, 0, stream>>>(bufA, FLAT, dw, FEAT, db,
                                              out + (size_t)n0 * OUTROW, OUTROW,
                                              chunk, FEAT, FLAT);
    }

    // mx = feats @ gru_k + bi   (reads feats back from the strided output rows)
    dim3 g2(NIMG / 64, 192 / 64);
    gemm_kernel<0><<<g2, 256, 0, stream>>>(out, OUTROW, gk, 192, gbv,
                                           mxbuf, 192, NIMG, 192, FEAT);

    gru_kernel<<<BATCH, 64, 0, stream>>>(mxbuf, grk, gbv, dones, state0, step0, out);
}

// Round 3
// 1738.908 us; speedup vs baseline: 1.6547x; 1.6547x over previous
//
#include <hip/hip_runtime.h>
#include <math.h>

#define BATCH 16
#define TSTEPS 128
#define UNITS 64
#define FEAT 512
#define FLAT 3136
#define OUTROW 576           // 512 + 64
#define OUT_FEATS (BATCH * TSTEPS * OUTROW)   // 1179648
#define MEMN 16

// ---------------- conv1: in [n,84,84,4] -> out [n,20,20,32], w[8,8,4,32], stride 4, ReLU
// grid (5 row-groups, chunk images). LDS: input slab 20x84x4 = 26.9 KB.
__global__ __launch_bounds__(256) void conv1_kernel(
    const float* __restrict__ in, const float* __restrict__ w,
    const float* __restrict__ bias, float* __restrict__ out, int n0)
{
    __shared__ float s[20 * 84 * 4];       // 6720 floats
    const int tid = threadIdx.x;
    const int rg  = blockIdx.x;            // 0..4 -> output rows 4rg..4rg+3
    const int img = n0 + blockIdx.y;

    {
        const float4* src = reinterpret_cast<const float4*>(
            in + (size_t)img * 28224 + (size_t)rg * 16 * 336);
        float4* dst = reinterpret_cast<float4*>(s);
        for (int i = tid; i < 1680; i += 256) dst[i] = src[i];
    }
    __syncthreads();

    const int oc   = tid & 31;
    const int pg   = tid >> 5;             // 0..7
    const int ly   = pg >> 1;              // 0..3 local out row
    const int half = pg & 1;               // 0..1 half-row (10 cols)

    float acc[10];
#pragma unroll
    for (int i = 0; i < 10; ++i) acc[i] = 0.f;

    for (int ky = 0; ky < 8; ++ky) {
        const float* srow = s + ((4 * ly + ky) * 84 + 40 * half) * 4;
#pragma unroll
        for (int kx = 0; kx < 8; ++kx) {
            const int widx = ((ky * 8 + kx) * 4) * 32 + oc;
            const float w0 = w[widx];
            const float w1 = w[widx + 32];
            const float w2 = w[widx + 64];
            const float w3 = w[widx + 96];
            const float* p = srow + kx * 4;
#pragma unroll
            for (int i = 0; i < 10; ++i) {
                const float4 v = *reinterpret_cast<const float4*>(p + i * 16);
                acc[i] = fmaf(v.x, w0, acc[i]);
                acc[i] = fmaf(v.y, w1, acc[i]);
                acc[i] = fmaf(v.z, w2, acc[i]);
                acc[i] = fmaf(v.w, w3, acc[i]);
            }
        }
    }

    const float b = bias[oc];
    float* ob = out + (size_t)blockIdx.y * 12800;
    const int y = 4 * rg + ly;
#pragma unroll
    for (int i = 0; i < 10; ++i) {
        const int x = half * 10 + i;
        ob[(y * 20 + x) * 32 + oc] = fmaxf(acc[i] + b, 0.f);
    }
}

// ---------------- conv2: in [n,20,20,32] -> out [n,9,9,64], w[4,4,32,64], stride 2, ReLU
__global__ __launch_bounds__(256) void conv2_kernel(
    const float* __restrict__ in, const float* __restrict__ w,
    const float* __restrict__ bias, float* __restrict__ out)
{
    __shared__ float s[12800];             // 51.2 KB
    const int tid = threadIdx.x;
    const int img = blockIdx.x;
    {
        const float4* src = reinterpret_cast<const float4*>(in + (size_t)img * 12800);
        float4* dst = reinterpret_cast<float4*>(s);
        for (int i = tid; i < 3200; i += 256) dst[i] = src[i];
    }
    __syncthreads();

    const int oc = tid & 63;
    const int pg = tid >> 6;               // 0..3

    float acc[21];
#pragma unroll
    for (int i = 0; i < 21; ++i) acc[i] = 0.f;

    int ib[21];
#pragma unroll
    for (int i = 0; i < 21; ++i) {
        int px = pg * 21 + i;              // 0..83
        int pc = px < 81 ? px : 80;
        int y = pc / 9, x = pc % 9;
        ib[i] = (y * 40 + x * 2) * 32;
    }

    for (int ky = 0; ky < 4; ++ky) {
        for (int kx = 0; kx < 4; ++kx) {
            const int woff = (ky * 4 + kx) * 2048 + oc;
            const int soff = (ky * 20 + kx) * 32;
#pragma unroll
            for (int icq = 0; icq < 8; ++icq) {
                const int ic = icq * 4;
                const float w0 = w[woff + (ic + 0) * 64];
                const float w1 = w[woff + (ic + 1) * 64];
                const float w2 = w[woff + (ic + 2) * 64];
                const float w3 = w[woff + (ic + 3) * 64];
                const float* p = s + soff + ic;
#pragma unroll
                for (int i = 0; i < 21; ++i) {
                    const float4 v = *reinterpret_cast<const float4*>(p + ib[i]);
                    acc[i] = fmaf(v.x, w0, acc[i]);
                    acc[i] = fmaf(v.y, w1, acc[i]);
                    acc[i] = fmaf(v.z, w2, acc[i]);
                    acc[i] = fmaf(v.w, w3, acc[i]);
                }
            }
        }
    }

    const float b = bias[oc];
    float* ob = out + (size_t)img * 5184;
#pragma unroll
    for (int i = 0; i < 21; ++i) {
        int px = pg * 21 + i;
        if (px < 81) ob[px * 64 + oc] = fmaxf(acc[i] + b, 0.f);
    }
}

// ---------------- conv3: in [n,9,9,64] -> out [n,7,7,64], w[3,3,64,64], stride 1, ReLU
__global__ __launch_bounds__(256) void conv3_kernel(
    const float* __restrict__ in, const float* __restrict__ w,
    const float* __restrict__ bias, float* __restrict__ out)
{
    __shared__ float s[5184];              // 20.7 KB
    const int tid = threadIdx.x;
    const int img = blockIdx.x;
    {
        const float4* src = reinterpret_cast<const float4*>(in + (size_t)img * 5184);
        float4* dst = reinterpret_cast<float4*>(s);
        for (int i = tid; i < 1296; i += 256) dst[i] = src[i];
    }
    __syncthreads();

    const int oc = tid & 63;
    const int pg = tid >> 6;               // 0..3

    float acc[13];
#pragma unroll
    for (int i = 0; i < 13; ++i) acc[i] = 0.f;

    int ib[13];
#pragma unroll
    for (int i = 0; i < 13; ++i) {
        int px = pg * 13 + i;              // 0..51
        int pc = px < 49 ? px : 48;
        int y = pc / 7, x = pc % 7;
        ib[i] = (y * 9 + x) * 64;
    }

    for (int ky = 0; ky < 3; ++ky) {
        for (int kx = 0; kx < 3; ++kx) {
            const int woff = (ky * 3 + kx) * 4096 + oc;
            const int soff = (ky * 9 + kx) * 64;
#pragma unroll
            for (int icq = 0; icq < 16; ++icq) {
                const int ic = icq * 4;
                const float w0 = w[woff + (ic + 0) * 64];
                const float w1 = w[woff + (ic + 1) * 64];
                const float w2 = w[woff + (ic + 2) * 64];
                const float w3 = w[woff + (ic + 3) * 64];
                const float* p = s + soff + ic;
#pragma unroll
                for (int i = 0; i < 13; ++i) {
                    const float4 v = *reinterpret_cast<const float4*>(p + ib[i]);
                    acc[i] = fmaf(v.x, w0, acc[i]);
                    acc[i] = fmaf(v.y, w1, acc[i]);
                    acc[i] = fmaf(v.z, w2, acc[i]);
                    acc[i] = fmaf(v.w, w3, acc[i]);
                }
            }
        }
    }

    const float b = bias[oc];
    float* ob = out + (size_t)img * 3136;
#pragma unroll
    for (int i = 0; i < 13; ++i) {
        int px = pg * 13 + i;
        if (px < 49) ob[px * 64 + oc] = fmaxf(acc[i] + b, 0.f);
    }
}

// ---------------- tiled fp32 GEMM: C[M,N] = act(A[M,K] @ B[K,N] + bias)
// BM=BN=64, BK=16, 256 threads, 4x4 micro-tile. Optional dual store to C2.
template <int RELU, int DUAL>
__global__ __launch_bounds__(256) void gemm_kernel(
    const float* __restrict__ A, int lda,
    const float* __restrict__ B, int ldb,
    const float* __restrict__ bias,
    float* __restrict__ C, int ldc,
    float* __restrict__ C2, int ldc2,
    int M, int N, int K)
{
    __shared__ float As[64][17];
    __shared__ float Bs[16][64];

    const int tid = threadIdx.x;
    const int bm0 = blockIdx.x * 64;
    const int bn0 = blockIdx.y * 64;
    const int tx = tid & 15, ty = tid >> 4;

    const int arow = tid >> 2;
    const int acol = (tid & 3) * 4;
    const int brow = tid >> 4;
    const int bcol = (tid & 15) * 4;

    const float* Ap = A + (size_t)(bm0 + arow) * lda + acol;
    const float* Bp = B + (size_t)brow * ldb + bn0 + bcol;

    float c[4][4];
#pragma unroll
    for (int i = 0; i < 4; ++i)
#pragma unroll
        for (int j = 0; j < 4; ++j) c[i][j] = 0.f;

    for (int k0 = 0; k0 < K; k0 += 16) {
        const float4 av = *reinterpret_cast<const float4*>(Ap + k0);
        const float4 bv = *reinterpret_cast<const float4*>(Bp + (size_t)k0 * ldb);
        __syncthreads();
        As[arow][acol + 0] = av.x;
        As[arow][acol + 1] = av.y;
        As[arow][acol + 2] = av.z;
        As[arow][acol + 3] = av.w;
        *reinterpret_cast<float4*>(&Bs[brow][bcol]) = bv;
        __syncthreads();
#pragma unroll
        for (int k = 0; k < 16; ++k) {
            float a0 = As[ty * 4 + 0][k];
            float a1 = As[ty * 4 + 1][k];
            float a2 = As[ty * 4 + 2][k];
            float a3 = As[ty * 4 + 3][k];
            float b0 = Bs[k][tx * 4 + 0];
            float b1 = Bs[k][tx * 4 + 1];
            float b2 = Bs[k][tx * 4 + 2];
            float b3 = Bs[k][tx * 4 + 3];
            c[0][0] = fmaf(a0, b0, c[0][0]); c[0][1] = fmaf(a0, b1, c[0][1]);
            c[0][2] = fmaf(a0, b2, c[0][2]); c[0][3] = fmaf(a0, b3, c[0][3]);
            c[1][0] = fmaf(a1, b0, c[1][0]); c[1][1] = fmaf(a1, b1, c[1][1]);
            c[1][2] = fmaf(a1, b2, c[1][2]); c[1][3] = fmaf(a1, b3, c[1][3]);
            c[2][0] = fmaf(a2, b0, c[2][0]); c[2][1] = fmaf(a2, b1, c[2][1]);
            c[2][2] = fmaf(a2, b2, c[2][2]); c[2][3] = fmaf(a2, b3, c[2][3]);
            c[3][0] = fmaf(a3, b0, c[3][0]); c[3][1] = fmaf(a3, b1, c[3][1]);
            c[3][2] = fmaf(a3, b2, c[3][2]); c[3][3] = fmaf(a3, b3, c[3][3]);
        }
    }

#pragma unroll
    for (int i = 0; i < 4; ++i) {
        const int row = bm0 + ty * 4 + i;
#pragma unroll
        for (int j = 0; j < 4; ++j) {
            const int col = bn0 + tx * 4 + j;
            float v = c[i][j] + bias[col];
            if (RELU) v = fmaxf(v, 0.f);
            C[(size_t)row * ldc + col] = v;
            if (DUAL) C2[(size_t)row * ldc2 + col] = v;
        }
    }
}

// ---------------- GRU recurrence: one block (64 threads, 1 wave) per batch row
__global__ __launch_bounds__(64) void gru_kernel(
    const float* __restrict__ mx,     // [2048,192] = feats @ gru_k + bi
    const float* __restrict__ rk,     // [64,192]
    const float* __restrict__ gb,     // [2,192]; br = gb + 192
    const int*   __restrict__ dones,  // [16,128]
    const float* __restrict__ state0, // [16,64]
    const int*   __restrict__ step0,  // [16]
    float* __restrict__ out)          // full out base
{
    __shared__ float rkl[64 * 192];   // 48 KB
    const int b = blockIdx.x;
    const int u = threadIdx.x;
    for (int i = u; i < 64 * 192; i += 64) rkl[i] = rk[i];
    __syncthreads();

    float h = state0[b * 64 + u];
    int step = step0[b];
    const float brz = gb[192 + u];
    const float brr = gb[192 + 64 + u];
    const float brh = gb[192 + 128 + u];

    for (int t = 0; t < TSTEPS; ++t) {
        const int bt = b * TSTEPS + t;
        float az = 0.f, ar = 0.f, ah = 0.f;
#pragma unroll 16
        for (int j = 0; j < 64; ++j) {
            const float hj = __shfl(h, j);
            az = fmaf(hj, rkl[j * 192 + u], az);
            ar = fmaf(hj, rkl[j * 192 + 64 + u], ar);
            ah = fmaf(hj, rkl[j * 192 + 128 + u], ah);
        }
        const float xz = mx[(size_t)bt * 192 + u];
        const float xr = mx[(size_t)bt * 192 + 64 + u];
        const float xh = mx[(size_t)bt * 192 + 128 + u];
        const float z = 1.f / (1.f + __expf(-(xz + az + brz)));
        const float r = 1.f / (1.f + __expf(-(xr + ar + brr)));
        const float hh = tanhf(xh + r * (ah + brh));
        const float hn = z * h + (1.f - z) * hh;

        out[(size_t)bt * OUTROW + 512 + u] = hn;

        step += 1;
        const int reset = (dones[bt] == 1) || ((step % MEMN) == 0);
        h = reset ? 0.f : hn;
        step = reset ? 0 : step;
    }

    out[OUT_FEATS + b * 64 + u] = h;
    if (u == 0) out[OUT_FEATS + 1024 + b] = (float)step;
}

extern "C" void kernel_launch(void* const* d_in, const int* in_sizes, int n_in,
                              void* d_out, int out_size, void* d_ws, size_t ws_size,
                              hipStream_t stream) {
    const float* inputs = (const float*)d_in[0];
    const int*   dones  = (const int*)d_in[1];
    const float* state0 = (const float*)d_in[2];
    const int*   step0  = (const int*)d_in[3];
    const float* c1w = (const float*)d_in[4];
    const float* c1b = (const float*)d_in[5];
    const float* c2w = (const float*)d_in[6];
    const float* c2b = (const float*)d_in[7];
    const float* c3w = (const float*)d_in[8];
    const float* c3b = (const float*)d_in[9];
    const float* dw  = (const float*)d_in[10];
    const float* db  = (const float*)d_in[11];
    const float* gk  = (const float*)d_in[12];
    const float* grk = (const float*)d_in[13];
    const float* gbv = (const float*)d_in[14];

    float* out = (float*)d_out;
    float* ws  = (float*)d_ws;

    const int NIMG = BATCH * TSTEPS;        // 2048
    const size_t mx_floats   = (size_t)NIMG * 192;   // 393216
    const size_t feat_floats = (size_t)NIMG * FEAT;  // 1048576
    const size_t avail = ws_size / sizeof(float);

    // Preferred layout: mx | featbuf | bufA | bufB  (d_out strictly write-only)
    const int opts[6] = {2048, 1024, 512, 256, 128, 64};
    int chunk = 0;
    for (int i = 0; i < 6; ++i) {
        size_t need = mx_floats + feat_floats + (size_t)opts[i] * (12800 + 5184);
        if (need <= avail) { chunk = opts[i]; break; }
    }
    const int use_featbuf = (chunk != 0);
    if (!use_featbuf) {
        for (int i = 0; i < 6; ++i) {
            size_t need = mx_floats + (size_t)opts[i] * (12800 + 5184);
            if (need <= avail) { chunk = opts[i]; break; }
        }
        if (chunk == 0) chunk = 64;  // last resort
    }

    float* mxbuf   = ws;
    float* featbuf = ws + mx_floats;
    float* bufA    = use_featbuf ? (featbuf + feat_floats) : (ws + mx_floats);
    float* bufB    = bufA + (size_t)chunk * 12800;

    for (int n0 = 0; n0 < NIMG; n0 += chunk) {
        dim3 g1(5, chunk);
        conv1_kernel<<<g1, 256, 0, stream>>>(inputs, c1w, c1b, bufA, n0);
        conv2_kernel<<<chunk, 256, 0, stream>>>(bufA, c2w, c2b, bufB);
        conv3_kernel<<<chunk, 256, 0, stream>>>(bufB, c3w, c3b, bufA);
        dim3 g(chunk / 64, FEAT / 64);
        if (use_featbuf) {
            gemm_kernel<1, 1><<<g, 256, 0, stream>>>(
                bufA, FLAT, dw, FEAT, db,
                out + (size_t)n0 * OUTROW, OUTROW,
                featbuf + (size_t)n0 * FEAT, FEAT,
                chunk, FEAT, FLAT);
        } else {
            gemm_kernel<1, 0><<<g, 256, 0, stream>>>(
                bufA, FLAT, dw, FEAT, db,
                out + (size_t)n0 * OUTROW, OUTROW,
                nullptr, 0,
                chunk, FEAT, FLAT);
        }
    }

    // mx = feats @ gru_k + bi
    dim3 g2(NIMG / 64, 192 / 64);
    if (use_featbuf) {
        gemm_kernel<0, 0><<<g2, 256, 0, stream>>>(featbuf, FEAT, gk, 192, gbv,
                                                  mxbuf, 192, nullptr, 0,
                                                  NIMG, 192, FEAT);
    } else {
        gemm_kernel<0, 0><<<g2, 256, 0, stream>>>(out, OUTROW, gk, 192, gbv,
                                                  mxbuf, 192, nullptr, 0,
                                                  NIMG, 192, FEAT);
    }

    gru_kernel<<<BATCH, 64, 0, stream>>>(mxbuf, grk, gbv, dones, state0, step0, out);
}

// Round 4
// 421.080 us; speedup vs baseline: 6.8332x; 4.1296x over previous
//
#include <hip/hip_runtime.h>
#include <math.h>

#define BATCH 16
#define TSTEPS 128
#define UNITS 64
#define FEAT 512
#define FLAT 3136
#define OUTROW 576           // 512 + 64
#define OUT_FEATS (BATCH * TSTEPS * OUTROW)   // 1179648
#define MEMN 16
#define NIMG 2048

typedef short bf16x8 __attribute__((ext_vector_type(8)));
typedef short short4v __attribute__((ext_vector_type(4)));
typedef float f32x4 __attribute__((ext_vector_type(4)));

__device__ __forceinline__ short f2b(float f) {
    unsigned u = __float_as_uint(f);
    unsigned r = (u + 0x7FFFu + ((u >> 16) & 1u)) >> 16;
    return (short)r;
}

// ---------------- weight packer: src fp32 [K][N] -> dst bf16 [K/8][N][8]
__global__ void pack_w_kernel(const float* __restrict__ src, short* __restrict__ dst, int N) {
    const int kg = blockIdx.x;
    const int tid = threadIdx.x;
    for (int t = tid; t < N * 8; t += 256) {
        int n = t >> 3, j = t & 7;
        dst[(size_t)kg * N * 8 + t] = f2b(src[(size_t)(kg * 8 + j) * N + n]);
    }
}

// ---------------- conv1 MFMA: in [n,84,84,4] fp32 -> out [n,400,32] bf16
// grid (5 row-groups, img). 128 threads = 2 waves; wave = n-tile (N=32 -> 2).
// K = 256 (ky 8 x kx 8 x c 4), kt = ky (32 k per ky). No swizzle (accept ~4-way).
__global__ __launch_bounds__(128) void conv1_mfma(
    const float* __restrict__ in, const short* __restrict__ wp,
    const float* __restrict__ bias, short* __restrict__ out)
{
    __shared__ short s[20 * 84 * 4];       // 26.9 KB bf16 slab
    const int tid = threadIdx.x;
    const int rg  = blockIdx.x;
    const int img = blockIdx.y;

    {
        const float4* src = reinterpret_cast<const float4*>(
            in + (size_t)img * 28224 + (size_t)rg * 5376);
        for (int i = tid; i < 1680; i += 128) {
            float4 v = src[i];
            short4v b; b.x = f2b(v.x); b.y = f2b(v.y); b.z = f2b(v.z); b.w = f2b(v.w);
            *reinterpret_cast<short4v*>(s + i * 4) = b;
        }
    }
    __syncthreads();

    const int w = tid >> 6, lane = tid & 63;
    const int row = lane & 15, g = lane >> 4;

    f32x4 acc[5];
#pragma unroll
    for (int i = 0; i < 5; ++i) acc[i] = (f32x4){0.f, 0.f, 0.f, 0.f};

    int soff[5];
#pragma unroll
    for (int mt = 0; mt < 5; ++mt) {
        int p = mt * 16 + row;             // 0..79
        int y = p / 20, x = p % 20;
        soff[mt] = ((y * 4) * 84 + x * 4 + g * 2) * 4;   // shorts
    }

    for (int ky = 0; ky < 8; ++ky) {
        const bf16x8 bfrag = *reinterpret_cast<const bf16x8*>(
            wp + ((size_t)(ky * 4 + g) * 32 + w * 16 + row) * 8);
#pragma unroll
        for (int mt = 0; mt < 5; ++mt) {
            const bf16x8 af = *reinterpret_cast<const bf16x8*>(s + soff[mt] + ky * 336);
            acc[mt] = __builtin_amdgcn_mfma_f32_16x16x32_bf16(af, bfrag, acc[mt], 0, 0, 0);
        }
    }

    const int n = w * 16 + row;
    const float bv = bias[n];
    short* ob = out + ((size_t)img * 400 + rg * 80) * 32;
#pragma unroll
    for (int mt = 0; mt < 5; ++mt)
#pragma unroll
        for (int r = 0; r < 4; ++r) {
            int p = mt * 16 + g * 4 + r;
            ob[p * 32 + n] = f2b(fmaxf(acc[mt][r] + bv, 0.f));
        }
}

// ---------------- conv2 MFMA: in [n,400,32] bf16 -> out [n,81,64] bf16
// 256 thr = 4 waves; wave = n-tile (N=64). M=81 -> 6 m-tiles. K=512, kt=(ky,kx).
// LDS swizzle: byte ^= ((q>>1)&7)<<4  (reader q stride 2 -> 8-way spread).
__global__ __launch_bounds__(256) void conv2_mfma(
    const short* __restrict__ in, const short* __restrict__ wp,
    const float* __restrict__ bias, short* __restrict__ out)
{
    __shared__ short s[400 * 32];          // 25.6 KB
    const int tid = threadIdx.x, img = blockIdx.x;
    {
        const short* src = in + (size_t)img * 12800;
        for (int i = tid; i < 1600; i += 256) {
            bf16x8 v = *reinterpret_cast<const bf16x8*>(src + i * 8);
            int q = i >> 2;
            unsigned byte = (unsigned)(i * 16);
            byte ^= ((q >> 1) & 7) << 4;
            *reinterpret_cast<bf16x8*>(reinterpret_cast<char*>(s) + byte) = v;
        }
    }
    __syncthreads();

    const int w = tid >> 6, lane = tid & 63;
    const int row = lane & 15, g = lane >> 4;

    f32x4 acc[6];
#pragma unroll
    for (int i = 0; i < 6; ++i) acc[i] = (f32x4){0.f, 0.f, 0.f, 0.f};

    int qb[6];
#pragma unroll
    for (int mt = 0; mt < 6; ++mt) {
        int p = mt * 16 + row; if (p > 80) p = 80;
        int y = p / 9, x = p % 9;
        qb[mt] = y * 40 + x * 2;
    }

    for (int kt = 0; kt < 16; ++kt) {
        const int ky = kt >> 2, kx = kt & 3;
        const bf16x8 bfrag = *reinterpret_cast<const bf16x8*>(
            wp + ((size_t)(kt * 4 + g) * 64 + w * 16 + row) * 8);
        const int qoff = ky * 20 + kx;
#pragma unroll
        for (int mt = 0; mt < 6; ++mt) {
            int q = qb[mt] + qoff;
            unsigned byte = (unsigned)(q * 64 + g * 16);
            byte ^= ((q >> 1) & 7) << 4;
            const bf16x8 af = *reinterpret_cast<const bf16x8*>(
                reinterpret_cast<const char*>(s) + byte);
            acc[mt] = __builtin_amdgcn_mfma_f32_16x16x32_bf16(af, bfrag, acc[mt], 0, 0, 0);
        }
    }

    const int n = w * 16 + row;
    const float bv = bias[n];
    short* ob = out + (size_t)img * 5184;
#pragma unroll
    for (int mt = 0; mt < 6; ++mt)
#pragma unroll
        for (int r = 0; r < 4; ++r) {
            int p = mt * 16 + g * 4 + r;
            if (p < 81) ob[p * 64 + n] = f2b(fmaxf(acc[mt][r] + bv, 0.f));
        }
}

// ---------------- conv3 MFMA: in [n,81,64] bf16 -> out [n,3136] bf16
// M=49 -> 4 m-tiles. K=576, kt 0..17 = (kxy, ic-half). Swizzle ^((q&7)<<4).
__global__ __launch_bounds__(256) void conv3_mfma(
    const short* __restrict__ in, const short* __restrict__ wp,
    const float* __restrict__ bias, short* __restrict__ out)
{
    __shared__ short s[81 * 64];           // 10.4 KB
    const int tid = threadIdx.x, img = blockIdx.x;
    {
        const short* src = in + (size_t)img * 5184;
        for (int i = tid; i < 648; i += 256) {
            bf16x8 v = *reinterpret_cast<const bf16x8*>(src + i * 8);
            int q = i >> 3;
            unsigned byte = (unsigned)(i * 16);
            byte ^= (q & 7) << 4;
            *reinterpret_cast<bf16x8*>(reinterpret_cast<char*>(s) + byte) = v;
        }
    }
    __syncthreads();

    const int w = tid >> 6, lane = tid & 63;
    const int row = lane & 15, g = lane >> 4;

    f32x4 acc[4];
#pragma unroll
    for (int i = 0; i < 4; ++i) acc[i] = (f32x4){0.f, 0.f, 0.f, 0.f};

    int qb[4];
#pragma unroll
    for (int mt = 0; mt < 4; ++mt) {
        int p = mt * 16 + row; if (p > 48) p = 48;
        int y = p / 7, x = p % 7;
        qb[mt] = y * 9 + x;
    }

    for (int kt = 0; kt < 18; ++kt) {
        const int kxy = kt >> 1;
        const int ky = kxy / 3, kx = kxy - ky * 3;
        const int coff = (kt & 1) * 64 + g * 16;   // byte offset within pixel row
        const bf16x8 bfrag = *reinterpret_cast<const bf16x8*>(
            wp + ((size_t)(kt * 4 + g) * 64 + w * 16 + row) * 8);
        const int qoff = ky * 9 + kx;
#pragma unroll
        for (int mt = 0; mt < 4; ++mt) {
            int q = qb[mt] + qoff;
            unsigned byte = (unsigned)(q * 128 + coff);
            byte ^= (q & 7) << 4;
            const bf16x8 af = *reinterpret_cast<const bf16x8*>(
                reinterpret_cast<const char*>(s) + byte);
            acc[mt] = __builtin_amdgcn_mfma_f32_16x16x32_bf16(af, bfrag, acc[mt], 0, 0, 0);
        }
    }

    const int n = w * 16 + row;
    const float bv = bias[n];
    short* ob = out + (size_t)img * 3136;
#pragma unroll
    for (int mt = 0; mt < 4; ++mt)
#pragma unroll
        for (int r = 0; r < 4; ++r) {
            int p = mt * 16 + g * 4 + r;
            if (p < 49) ob[p * 64 + n] = f2b(fmaxf(acc[mt][r] + bv, 0.f));
        }
}

// ---------------- dense MFMA: feats = relu(A[2048,3136] @ W + b)
// 512 thr = 8 waves; wave w: n-tile w&3, m-tiles {2*(w>>2), +1}. grid (32, 8).
// Writes fp32 to d_out (stride 576) and bf16 copy to featb.
__global__ __launch_bounds__(512) void dense_mfma(
    const short* __restrict__ A, const short* __restrict__ wp,
    const float* __restrict__ bias, float* __restrict__ outp,
    short* __restrict__ featb)
{
    const int tid = threadIdx.x;
    const int w = tid >> 6, lane = tid & 63;
    const int row = lane & 15, g = lane >> 4;
    const int bm0 = blockIdx.x * 64, bn0 = blockIdx.y * 64;
    const int nt = w & 3, mtb = (w >> 2) * 2;

    f32x4 acc0 = (f32x4){0.f, 0.f, 0.f, 0.f};
    f32x4 acc1 = (f32x4){0.f, 0.f, 0.f, 0.f};

    const short* a0 = A + (size_t)(bm0 + mtb * 16 + row) * FLAT + g * 8;
    const short* a1 = a0 + 16 * FLAT;
    const short* bp = wp + ((size_t)g * FEAT + bn0 + nt * 16 + row) * 8;

    for (int kt = 0; kt < 98; ++kt) {
        const bf16x8 b  = *reinterpret_cast<const bf16x8*>(bp + (size_t)kt * 4 * FEAT * 8);
        const bf16x8 x0 = *reinterpret_cast<const bf16x8*>(a0 + kt * 32);
        const bf16x8 x1 = *reinterpret_cast<const bf16x8*>(a1 + kt * 32);
        acc0 = __builtin_amdgcn_mfma_f32_16x16x32_bf16(x0, b, acc0, 0, 0, 0);
        acc1 = __builtin_amdgcn_mfma_f32_16x16x32_bf16(x1, b, acc1, 0, 0, 0);
    }

    const int n = bn0 + nt * 16 + row;
    const float bv = bias[n];
#pragma unroll
    for (int r = 0; r < 4; ++r) {
        int m0 = bm0 + mtb * 16 + g * 4 + r;
        float v0 = fmaxf(acc0[r] + bv, 0.f);
        outp[(size_t)m0 * OUTROW + n] = v0;
        featb[(size_t)m0 * FEAT + n] = f2b(v0);
        int m1 = m0 + 16;
        float v1 = fmaxf(acc1[r] + bv, 0.f);
        outp[(size_t)m1 * OUTROW + n] = v1;
        featb[(size_t)m1 * FEAT + n] = f2b(v1);
    }
}

// ---------------- mx MFMA: mx[2048,192] = featb @ gru_k + bi. grid (32, 3).
__global__ __launch_bounds__(512) void mx_mfma(
    const short* __restrict__ A, const short* __restrict__ wp,
    const float* __restrict__ gb, float* __restrict__ mx)
{
    const int tid = threadIdx.x;
    const int w = tid >> 6, lane = tid & 63;
    const int row = lane & 15, g = lane >> 4;
    const int bm0 = blockIdx.x * 64, bn0 = blockIdx.y * 64;
    const int nt = w & 3, mtb = (w >> 2) * 2;

    f32x4 acc0 = (f32x4){0.f, 0.f, 0.f, 0.f};
    f32x4 acc1 = (f32x4){0.f, 0.f, 0.f, 0.f};

    const short* a0 = A + (size_t)(bm0 + mtb * 16 + row) * FEAT + g * 8;
    const short* a1 = a0 + 16 * FEAT;
    const short* bp = wp + ((size_t)g * 192 + bn0 + nt * 16 + row) * 8;

    for (int kt = 0; kt < 16; ++kt) {
        const bf16x8 b  = *reinterpret_cast<const bf16x8*>(bp + (size_t)kt * 4 * 192 * 8);
        const bf16x8 x0 = *reinterpret_cast<const bf16x8*>(a0 + kt * 32);
        const bf16x8 x1 = *reinterpret_cast<const bf16x8*>(a1 + kt * 32);
        acc0 = __builtin_amdgcn_mfma_f32_16x16x32_bf16(x0, b, acc0, 0, 0, 0);
        acc1 = __builtin_amdgcn_mfma_f32_16x16x32_bf16(x1, b, acc1, 0, 0, 0);
    }

    const int n = bn0 + nt * 16 + row;
    const float bv = gb[n];                 // bi row
#pragma unroll
    for (int r = 0; r < 4; ++r) {
        int m0 = bm0 + mtb * 16 + g * 4 + r;
        mx[(size_t)m0 * 192 + n] = acc0[r] + bv;
        int m1 = m0 + 16;
        mx[(size_t)m1 * 192 + n] = acc1[r] + bv;
    }
}

// ---------------- GRU recurrence: one block (64 threads, 1 wave) per batch row
__global__ __launch_bounds__(64) void gru_kernel(
    const float* __restrict__ mx,     // [2048,192]
    const float* __restrict__ rk,     // [64,192]
    const float* __restrict__ gb,     // [2,192]; br = gb + 192
    const int*   __restrict__ dones,  // [16,128]
    const float* __restrict__ state0, // [16,64]
    const int*   __restrict__ step0,  // [16]
    float* __restrict__ out)
{
    __shared__ float rkl[64 * 192];   // 48 KB
    const int b = blockIdx.x;
    const int u = threadIdx.x;
    for (int i = u; i < 64 * 192; i += 64) rkl[i] = rk[i];
    __syncthreads();

    float h = state0[b * 64 + u];
    int step = step0[b];
    const float brz = gb[192 + u];
    const float brr = gb[192 + 64 + u];
    const float brh = gb[192 + 128 + u];

    for (int t = 0; t < TSTEPS; ++t) {
        const int bt = b * TSTEPS + t;
        float az = 0.f, ar = 0.f, ah = 0.f;
#pragma unroll 16
        for (int j = 0; j < 64; ++j) {
            const float hj = __shfl(h, j);
            az = fmaf(hj, rkl[j * 192 + u], az);
            ar = fmaf(hj, rkl[j * 192 + 64 + u], ar);
            ah = fmaf(hj, rkl[j * 192 + 128 + u], ah);
        }
        const float xz = mx[(size_t)bt * 192 + u];
        const float xr = mx[(size_t)bt * 192 + 64 + u];
        const float xh = mx[(size_t)bt * 192 + 128 + u];
        const float z = 1.f / (1.f + __expf(-(xz + az + brz)));
        const float r = 1.f / (1.f + __expf(-(xr + ar + brr)));
        const float hh = tanhf(xh + r * (ah + brh));
        const float hn = z * h + (1.f - z) * hh;

        out[(size_t)bt * OUTROW + 512 + u] = hn;

        step += 1;
        const int reset = (dones[bt] == 1) || ((step % MEMN) == 0);
        h = reset ? 0.f : hn;
        step = reset ? 0 : step;
    }

    out[OUT_FEATS + b * 64 + u] = h;
    if (u == 0) out[OUT_FEATS + 1024 + b] = (float)step;
}

extern "C" void kernel_launch(void* const* d_in, const int* in_sizes, int n_in,
                              void* d_out, int out_size, void* d_ws, size_t ws_size,
                              hipStream_t stream) {
    const float* inputs = (const float*)d_in[0];
    const int*   dones  = (const int*)d_in[1];
    const float* state0 = (const float*)d_in[2];
    const int*   step0  = (const int*)d_in[3];
    const float* c1w = (const float*)d_in[4];
    const float* c1b = (const float*)d_in[5];
    const float* c2w = (const float*)d_in[6];
    const float* c2b = (const float*)d_in[7];
    const float* c3w = (const float*)d_in[8];
    const float* c3b = (const float*)d_in[9];
    const float* dw  = (const float*)d_in[10];
    const float* db  = (const float*)d_in[11];
    const float* gk  = (const float*)d_in[12];
    const float* grk = (const float*)d_in[13];
    const float* gbv = (const float*)d_in[14];

    float* out = (float*)d_out;

    // workspace carve (256 B aligned). Total ~94 MB.
    char* p = (char*)d_ws;
    auto alloc = [&](size_t bytes) {
        char* r = p; p += (bytes + 255) & ~(size_t)255; return r;
    };
    short* wp1 = (short*)alloc((size_t)8192 * 2);          // conv1 w packed
    short* wp2 = (short*)alloc((size_t)32768 * 2);
    short* wp3 = (short*)alloc((size_t)36864 * 2);
    short* wpd = (short*)alloc((size_t)FLAT * FEAT * 2);
    short* wpg = (short*)alloc((size_t)FEAT * 192 * 2);
    short* c1o = (short*)alloc((size_t)NIMG * 12800 * 2);
    short* c2o = (short*)alloc((size_t)NIMG * 5184 * 2);
    short* c3o = (short*)alloc((size_t)NIMG * FLAT * 2);
    short* ftb = (short*)alloc((size_t)NIMG * FEAT * 2);
    float* mxb = (float*)alloc((size_t)NIMG * 192 * 4);

    // pack weights to bf16 fragment-major
    pack_w_kernel<<<32,  256, 0, stream>>>(c1w, wp1, 32);
    pack_w_kernel<<<64,  256, 0, stream>>>(c2w, wp2, 64);
    pack_w_kernel<<<72,  256, 0, stream>>>(c3w, wp3, 64);
    pack_w_kernel<<<392, 256, 0, stream>>>(dw,  wpd, FEAT);
    pack_w_kernel<<<64,  256, 0, stream>>>(gk,  wpg, 192);

    dim3 g1(5, NIMG);
    conv1_mfma<<<g1, 128, 0, stream>>>(inputs, wp1, c1b, c1o);
    conv2_mfma<<<NIMG, 256, 0, stream>>>(c1o, wp2, c2b, c2o);
    conv3_mfma<<<NIMG, 256, 0, stream>>>(c2o, wp3, c3b, c3o);

    dim3 gd(NIMG / 64, FEAT / 64);
    dense_mfma<<<gd, 512, 0, stream>>>(c3o, wpd, db, out, ftb);

    dim3 gm(NIMG / 64, 192 / 64);
    mx_mfma<<<gm, 512, 0, stream>>>(ftb, wpg, gbv, mxb);

    gru_kernel<<<BATCH, 64, 0, stream>>>(mxb, grk, gbv, dones, state0, step0, out);
}

// Round 5
// 244.771 us; speedup vs baseline: 11.7551x; 1.7203x over previous
//
#include <hip/hip_runtime.h>
#include <math.h>

#define BATCH 16
#define TSTEPS 128
#define UNITS 64
#define FEAT 512
#define FLAT 3136
#define OUTROW 576           // 512 + 64
#define OUT_FEATS (BATCH * TSTEPS * OUTROW)   // 1179648
#define MEMN 16
#define NIMG 2048

typedef short bf16x8 __attribute__((ext_vector_type(8)));
typedef short short4v __attribute__((ext_vector_type(4)));
typedef float f32x4 __attribute__((ext_vector_type(4)));

__device__ __forceinline__ short f2b(float f) {
    unsigned u = __float_as_uint(f);
    unsigned r = (u + 0x7FFFu + ((u >> 16) & 1u)) >> 16;
    return (short)r;
}

// ---------------- weight packer: src fp32 [K][N] -> dst bf16 [K/8][N][8]
__global__ void pack_w_kernel(const float* __restrict__ src, short* __restrict__ dst, int N) {
    const int kg = blockIdx.x;
    const int tid = threadIdx.x;
    for (int t = tid; t < N * 8; t += 256) {
        int n = t >> 3, j = t & 7;
        dst[(size_t)kg * N * 8 + t] = f2b(src[(size_t)(kg * 8 + j) * N + n]);
    }
}

// ---------------- conv1 MFMA: in [n,84,84,4] fp32 -> out [n,400,32] bf16
__global__ __launch_bounds__(128) void conv1_mfma(
    const float* __restrict__ in, const short* __restrict__ wp,
    const float* __restrict__ bias, short* __restrict__ out)
{
    __shared__ short s[20 * 84 * 4];       // 26.9 KB bf16 slab
    const int tid = threadIdx.x;
    const int rg  = blockIdx.x;
    const int img = blockIdx.y;

    {
        const float4* src = reinterpret_cast<const float4*>(
            in + (size_t)img * 28224 + (size_t)rg * 5376);
        for (int i = tid; i < 1680; i += 128) {
            float4 v = src[i];
            short4v b; b.x = f2b(v.x); b.y = f2b(v.y); b.z = f2b(v.z); b.w = f2b(v.w);
            *reinterpret_cast<short4v*>(s + i * 4) = b;
        }
    }
    __syncthreads();

    const int w = tid >> 6, lane = tid & 63;
    const int row = lane & 15, g = lane >> 4;

    f32x4 acc[5];
#pragma unroll
    for (int i = 0; i < 5; ++i) acc[i] = (f32x4){0.f, 0.f, 0.f, 0.f};

    int soff[5];
#pragma unroll
    for (int mt = 0; mt < 5; ++mt) {
        int p = mt * 16 + row;             // 0..79
        int y = p / 20, x = p % 20;
        soff[mt] = ((y * 4) * 84 + x * 4 + g * 2) * 4;   // shorts
    }

    for (int ky = 0; ky < 8; ++ky) {
        const bf16x8 bfrag = *reinterpret_cast<const bf16x8*>(
            wp + ((size_t)(ky * 4 + g) * 32 + w * 16 + row) * 8);
#pragma unroll
        for (int mt = 0; mt < 5; ++mt) {
            const bf16x8 af = *reinterpret_cast<const bf16x8*>(s + soff[mt] + ky * 336);
            acc[mt] = __builtin_amdgcn_mfma_f32_16x16x32_bf16(af, bfrag, acc[mt], 0, 0, 0);
        }
    }

    const int n = w * 16 + row;
    const float bv = bias[n];
    short* ob = out + ((size_t)img * 400 + rg * 80) * 32;
#pragma unroll
    for (int mt = 0; mt < 5; ++mt)
#pragma unroll
        for (int r = 0; r < 4; ++r) {
            int p = mt * 16 + g * 4 + r;
            ob[p * 32 + n] = f2b(fmaxf(acc[mt][r] + bv, 0.f));
        }
}

// ---------------- conv2 MFMA: in [n,400,32] bf16 -> out [n,81,64] bf16
__global__ __launch_bounds__(256) void conv2_mfma(
    const short* __restrict__ in, const short* __restrict__ wp,
    const float* __restrict__ bias, short* __restrict__ out)
{
    __shared__ short s[400 * 32];          // 25.6 KB
    const int tid = threadIdx.x, img = blockIdx.x;
    {
        const short* src = in + (size_t)img * 12800;
        for (int i = tid; i < 1600; i += 256) {
            bf16x8 v = *reinterpret_cast<const bf16x8*>(src + i * 8);
            int q = i >> 2;
            unsigned byte = (unsigned)(i * 16);
            byte ^= ((q >> 1) & 7) << 4;
            *reinterpret_cast<bf16x8*>(reinterpret_cast<char*>(s) + byte) = v;
        }
    }
    __syncthreads();

    const int w = tid >> 6, lane = tid & 63;
    const int row = lane & 15, g = lane >> 4;

    f32x4 acc[6];
#pragma unroll
    for (int i = 0; i < 6; ++i) acc[i] = (f32x4){0.f, 0.f, 0.f, 0.f};

    int qb[6];
#pragma unroll
    for (int mt = 0; mt < 6; ++mt) {
        int p = mt * 16 + row; if (p > 80) p = 80;
        int y = p / 9, x = p % 9;
        qb[mt] = y * 40 + x * 2;
    }

    for (int kt = 0; kt < 16; ++kt) {
        const int ky = kt >> 2, kx = kt & 3;
        const bf16x8 bfrag = *reinterpret_cast<const bf16x8*>(
            wp + ((size_t)(kt * 4 + g) * 64 + w * 16 + row) * 8);
        const int qoff = ky * 20 + kx;
#pragma unroll
        for (int mt = 0; mt < 6; ++mt) {
            int q = qb[mt] + qoff;
            unsigned byte = (unsigned)(q * 64 + g * 16);
            byte ^= ((q >> 1) & 7) << 4;
            const bf16x8 af = *reinterpret_cast<const bf16x8*>(
                reinterpret_cast<const char*>(s) + byte);
            acc[mt] = __builtin_amdgcn_mfma_f32_16x16x32_bf16(af, bfrag, acc[mt], 0, 0, 0);
        }
    }

    const int n = w * 16 + row;
    const float bv = bias[n];
    short* ob = out + (size_t)img * 5184;
#pragma unroll
    for (int mt = 0; mt < 6; ++mt)
#pragma unroll
        for (int r = 0; r < 4; ++r) {
            int p = mt * 16 + g * 4 + r;
            if (p < 81) ob[p * 64 + n] = f2b(fmaxf(acc[mt][r] + bv, 0.f));
        }
}

// ---------------- conv3 MFMA: in [n,81,64] bf16 -> out [n,3136] bf16
__global__ __launch_bounds__(256) void conv3_mfma(
    const short* __restrict__ in, const short* __restrict__ wp,
    const float* __restrict__ bias, short* __restrict__ out)
{
    __shared__ short s[81 * 64];           // 10.4 KB
    const int tid = threadIdx.x, img = blockIdx.x;
    {
        const short* src = in + (size_t)img * 5184;
        for (int i = tid; i < 648; i += 256) {
            bf16x8 v = *reinterpret_cast<const bf16x8*>(src + i * 8);
            int q = i >> 3;
            unsigned byte = (unsigned)(i * 16);
            byte ^= (q & 7) << 4;
            *reinterpret_cast<bf16x8*>(reinterpret_cast<char*>(s) + byte) = v;
        }
    }
    __syncthreads();

    const int w = tid >> 6, lane = tid & 63;
    const int row = lane & 15, g = lane >> 4;

    f32x4 acc[4];
#pragma unroll
    for (int i = 0; i < 4; ++i) acc[i] = (f32x4){0.f, 0.f, 0.f, 0.f};

    int qb[4];
#pragma unroll
    for (int mt = 0; mt < 4; ++mt) {
        int p = mt * 16 + row; if (p > 48) p = 48;
        int y = p / 7, x = p % 7;
        qb[mt] = y * 9 + x;
    }

    for (int kt = 0; kt < 18; ++kt) {
        const int kxy = kt >> 1;
        const int ky = kxy / 3, kx = kxy - ky * 3;
        const int coff = (kt & 1) * 64 + g * 16;   // byte offset within pixel row
        const bf16x8 bfrag = *reinterpret_cast<const bf16x8*>(
            wp + ((size_t)(kt * 4 + g) * 64 + w * 16 + row) * 8);
        const int qoff = ky * 9 + kx;
#pragma unroll
        for (int mt = 0; mt < 4; ++mt) {
            int q = qb[mt] + qoff;
            unsigned byte = (unsigned)(q * 128 + coff);
            byte ^= (q & 7) << 4;
            const bf16x8 af = *reinterpret_cast<const bf16x8*>(
                reinterpret_cast<const char*>(s) + byte);
            acc[mt] = __builtin_amdgcn_mfma_f32_16x16x32_bf16(af, bfrag, acc[mt], 0, 0, 0);
        }
    }

    const int n = w * 16 + row;
    const float bv = bias[n];
    short* ob = out + (size_t)img * 3136;
#pragma unroll
    for (int mt = 0; mt < 4; ++mt)
#pragma unroll
        for (int r = 0; r < 4; ++r) {
            int p = mt * 16 + g * 4 + r;
            if (p < 49) ob[p * 64 + n] = f2b(fmaxf(acc[mt][r] + bv, 0.f));
        }
}

// ---------------- dense MFMA: feats = relu(A[2048,3136] @ W + b)
__global__ __launch_bounds__(512) void dense_mfma(
    const short* __restrict__ A, const short* __restrict__ wp,
    const float* __restrict__ bias, float* __restrict__ outp,
    short* __restrict__ featb)
{
    const int tid = threadIdx.x;
    const int w = tid >> 6, lane = tid & 63;
    const int row = lane & 15, g = lane >> 4;
    const int bm0 = blockIdx.x * 64, bn0 = blockIdx.y * 64;
    const int nt = w & 3, mtb = (w >> 2) * 2;

    f32x4 acc0 = (f32x4){0.f, 0.f, 0.f, 0.f};
    f32x4 acc1 = (f32x4){0.f, 0.f, 0.f, 0.f};

    const short* a0 = A + (size_t)(bm0 + mtb * 16 + row) * FLAT + g * 8;
    const short* a1 = a0 + 16 * FLAT;
    const short* bp = wp + ((size_t)g * FEAT + bn0 + nt * 16 + row) * 8;

    for (int kt = 0; kt < 98; ++kt) {
        const bf16x8 b  = *reinterpret_cast<const bf16x8*>(bp + (size_t)kt * 4 * FEAT * 8);
        const bf16x8 x0 = *reinterpret_cast<const bf16x8*>(a0 + kt * 32);
        const bf16x8 x1 = *reinterpret_cast<const bf16x8*>(a1 + kt * 32);
        acc0 = __builtin_amdgcn_mfma_f32_16x16x32_bf16(x0, b, acc0, 0, 0, 0);
        acc1 = __builtin_amdgcn_mfma_f32_16x16x32_bf16(x1, b, acc1, 0, 0, 0);
    }

    const int n = bn0 + nt * 16 + row;
    const float bv = bias[n];
#pragma unroll
    for (int r = 0; r < 4; ++r) {
        int m0 = bm0 + mtb * 16 + g * 4 + r;
        float v0 = fmaxf(acc0[r] + bv, 0.f);
        outp[(size_t)m0 * OUTROW + n] = v0;
        featb[(size_t)m0 * FEAT + n] = f2b(v0);
        int m1 = m0 + 16;
        float v1 = fmaxf(acc1[r] + bv, 0.f);
        outp[(size_t)m1 * OUTROW + n] = v1;
        featb[(size_t)m1 * FEAT + n] = f2b(v1);
    }
}

// ---------------- mx MFMA: mx[2048,192] = featb @ gru_k + bi. grid (32, 3).
__global__ __launch_bounds__(512) void mx_mfma(
    const short* __restrict__ A, const short* __restrict__ wp,
    const float* __restrict__ gb, float* __restrict__ mx)
{
    const int tid = threadIdx.x;
    const int w = tid >> 6, lane = tid & 63;
    const int row = lane & 15, g = lane >> 4;
    const int bm0 = blockIdx.x * 64, bn0 = blockIdx.y * 64;
    const int nt = w & 3, mtb = (w >> 2) * 2;

    f32x4 acc0 = (f32x4){0.f, 0.f, 0.f, 0.f};
    f32x4 acc1 = (f32x4){0.f, 0.f, 0.f, 0.f};

    const short* a0 = A + (size_t)(bm0 + mtb * 16 + row) * FEAT + g * 8;
    const short* a1 = a0 + 16 * FEAT;
    const short* bp = wp + ((size_t)g * 192 + bn0 + nt * 16 + row) * 8;

    for (int kt = 0; kt < 16; ++kt) {
        const bf16x8 b  = *reinterpret_cast<const bf16x8*>(bp + (size_t)kt * 4 * 192 * 8);
        const bf16x8 x0 = *reinterpret_cast<const bf16x8*>(a0 + kt * 32);
        const bf16x8 x1 = *reinterpret_cast<const bf16x8*>(a1 + kt * 32);
        acc0 = __builtin_amdgcn_mfma_f32_16x16x32_bf16(x0, b, acc0, 0, 0, 0);
        acc1 = __builtin_amdgcn_mfma_f32_16x16x32_bf16(x1, b, acc1, 0, 0, 0);
    }

    const int n = bn0 + nt * 16 + row;
    const float bv = gb[n];                 // bi row
#pragma unroll
    for (int r = 0; r < 4; ++r) {
        int m0 = bm0 + mtb * 16 + g * 4 + r;
        mx[(size_t)m0 * 192 + n] = acc0[r] + bv;
        int m1 = m0 + 16;
        mx[(size_t)m1 * 192 + n] = acc1[r] + bv;
    }
}

// ---------------- segment precompute: step dynamics depend only on dones/step0.
// Emits per-batch segments (start, len<=16, reset_at_end) + final step counter.
__global__ __launch_bounds__(64) void seg_kernel(
    const int* __restrict__ dones, const int* __restrict__ step0,
    int* __restrict__ seg, int* __restrict__ nseg, float* __restrict__ out)
{
    const int b = threadIdx.x;
    if (b >= BATCH) return;
    int step = step0[b];
    int n = 0, start = 0;
    for (int t = 0; t < TSTEPS; ++t) {
        step += 1;
        const int reset = (dones[b * TSTEPS + t] == 1) || ((step % MEMN) == 0);
        if (reset) step = 0;
        if (reset || t == TSTEPS - 1) {
            seg[b * TSTEPS + n] = start | ((t - start + 1) << 8) | (reset << 16);
            n += 1;
            start = t + 1;
        }
    }
    nseg[b] = n;
    out[OUT_FEATS + 1024 + b] = (float)step;
}

// ---------------- GRU segments: one wave per segment (<=16 steps, no resets inside).
// Weights read from global (L2-broadcast across blocks); h broadcast via shfl.
__global__ __launch_bounds__(64) void gru_seg_kernel(
    const float* __restrict__ mx,     // [2048,192]
    const float* __restrict__ rk,     // [64,192]
    const float* __restrict__ gb,     // [2,192]; br = gb + 192
    const float* __restrict__ state0, // [16,64]
    const int*   __restrict__ seg, const int* __restrict__ nseg,
    float* __restrict__ out)
{
    const int b = blockIdx.x >> 7;
    const int i = blockIdx.x & 127;
    if (i >= nseg[b]) return;
    const int e = seg[b * TSTEPS + i];
    const int start = e & 255;
    const int len   = (e >> 8) & 255;
    const int rend  = (e >> 16) & 1;

    const int u = threadIdx.x;
    float h = (start == 0) ? state0[b * 64 + u] : 0.f;
    const float brz = gb[192 + u];
    const float brr = gb[192 + 64 + u];
    const float brh = gb[192 + 128 + u];

    for (int k = 0; k < len; ++k) {
        const int bt = b * TSTEPS + start + k;
        float az = 0.f, ar = 0.f, ah = 0.f;
#pragma unroll 16
        for (int j = 0; j < 64; ++j) {
            const float hj = __shfl(h, j);
            az = fmaf(hj, rk[j * 192 + u], az);
            ar = fmaf(hj, rk[j * 192 + 64 + u], ar);
            ah = fmaf(hj, rk[j * 192 + 128 + u], ah);
        }
        const float xz = mx[(size_t)bt * 192 + u];
        const float xr = mx[(size_t)bt * 192 + 64 + u];
        const float xh = mx[(size_t)bt * 192 + 128 + u];
        const float z = 1.f / (1.f + __expf(-(xz + az + brz)));
        const float r = 1.f / (1.f + __expf(-(xr + ar + brr)));
        const float hh = tanhf(xh + r * (ah + brh));
        const float hn = z * h + (1.f - z) * hh;

        out[(size_t)bt * OUTROW + 512 + u] = hn;
        h = hn;
    }

    if (start + len == TSTEPS) {
        out[OUT_FEATS + b * 64 + u] = rend ? 0.f : h;
    }
}

extern "C" void kernel_launch(void* const* d_in, const int* in_sizes, int n_in,
                              void* d_out, int out_size, void* d_ws, size_t ws_size,
                              hipStream_t stream) {
    const float* inputs = (const float*)d_in[0];
    const int*   dones  = (const int*)d_in[1];
    const float* state0 = (const float*)d_in[2];
    const int*   step0  = (const int*)d_in[3];
    const float* c1w = (const float*)d_in[4];
    const float* c1b = (const float*)d_in[5];
    const float* c2w = (const float*)d_in[6];
    const float* c2b = (const float*)d_in[7];
    const float* c3w = (const float*)d_in[8];
    const float* c3b = (const float*)d_in[9];
    const float* dw  = (const float*)d_in[10];
    const float* db  = (const float*)d_in[11];
    const float* gk  = (const float*)d_in[12];
    const float* grk = (const float*)d_in[13];
    const float* gbv = (const float*)d_in[14];

    float* out = (float*)d_out;

    // workspace carve (256 B aligned). Total ~94 MB.
    char* p = (char*)d_ws;
    auto alloc = [&](size_t bytes) {
        char* r = p; p += (bytes + 255) & ~(size_t)255; return r;
    };
    short* wp1 = (short*)alloc((size_t)8192 * 2);          // conv1 w packed
    short* wp2 = (short*)alloc((size_t)32768 * 2);
    short* wp3 = (short*)alloc((size_t)36864 * 2);
    short* wpd = (short*)alloc((size_t)FLAT * FEAT * 2);
    short* wpg = (short*)alloc((size_t)FEAT * 192 * 2);
    short* c1o = (short*)alloc((size_t)NIMG * 12800 * 2);
    short* c2o = (short*)alloc((size_t)NIMG * 5184 * 2);
    short* c3o = (short*)alloc((size_t)NIMG * FLAT * 2);
    short* ftb = (short*)alloc((size_t)NIMG * FEAT * 2);
    float* mxb = (float*)alloc((size_t)NIMG * 192 * 4);
    int*   segb = (int*)alloc((size_t)BATCH * TSTEPS * 4);
    int*   nsegb = (int*)alloc((size_t)BATCH * 4);

    // pack weights to bf16 fragment-major
    pack_w_kernel<<<32,  256, 0, stream>>>(c1w, wp1, 32);
    pack_w_kernel<<<64,  256, 0, stream>>>(c2w, wp2, 64);
    pack_w_kernel<<<72,  256, 0, stream>>>(c3w, wp3, 64);
    pack_w_kernel<<<392, 256, 0, stream>>>(dw,  wpd, FEAT);
    pack_w_kernel<<<64,  256, 0, stream>>>(gk,  wpg, 192);

    // segment precompute (independent of conv path; launch early)
    seg_kernel<<<1, 64, 0, stream>>>(dones, step0, segb, nsegb, out);

    dim3 g1(5, NIMG);
    conv1_mfma<<<g1, 128, 0, stream>>>(inputs, wp1, c1b, c1o);
    conv2_mfma<<<NIMG, 256, 0, stream>>>(c1o, wp2, c2b, c2o);
    conv3_mfma<<<NIMG, 256, 0, stream>>>(c2o, wp3, c3b, c3o);

    dim3 gd(NIMG / 64, FEAT / 64);
    dense_mfma<<<gd, 512, 0, stream>>>(c3o, wpd, db, out, ftb);

    dim3 gm(NIMG / 64, 192 / 64);
    mx_mfma<<<gm, 512, 0, stream>>>(ftb, wpg, gbv, mxb);

    gru_seg_kernel<<<BATCH * TSTEPS, 64, 0, stream>>>(
        mxb, grk, gbv, state0, segb, nsegb, out);
}

// Round 6
// 223.386 us; speedup vs baseline: 12.8804x; 1.0957x over previous
//
#include <hip/hip_runtime.h>
#include <math.h>

#define BATCH 16
#define TSTEPS 128
#define UNITS 64
#define FEAT 512
#define FLAT 3136
#define OUTROW 576           // 512 + 64
#define OUT_FEATS (BATCH * TSTEPS * OUTROW)   // 1179648
#define MEMN 16
#define NIMG 2048

typedef short bf16x8 __attribute__((ext_vector_type(8)));
typedef short short4v __attribute__((ext_vector_type(4)));
typedef float f32x4 __attribute__((ext_vector_type(4)));

__device__ __forceinline__ short f2b(float f) {
    unsigned u = __float_as_uint(f);
    unsigned r = (u + 0x7FFFu + ((u >> 16) & 1u)) >> 16;
    return (short)r;
}

// ---------------- mega-pack: all weight matrices fp32 [K][N] -> bf16 [K/8][N][8]
// (coalesced via LDS transpose) + seg precompute as the last block.
__global__ __launch_bounds__(256) void megapack(
    const float* __restrict__ dw, const float* __restrict__ gk,
    const float* __restrict__ c1w, const float* __restrict__ c2w,
    const float* __restrict__ c3w,
    short* __restrict__ wpd, short* __restrict__ wpg, short* __restrict__ wp1,
    short* __restrict__ wp2, short* __restrict__ wp3,
    const int* __restrict__ dones, const int* __restrict__ step0,
    int* __restrict__ seg, int* __restrict__ nseg, float* __restrict__ out)
{
    __shared__ float lds[8 * 513];         // 16.4 KB, pad 513 -> conflict-free
    const int blk = blockIdx.x;
    const int tid = threadIdx.x;

    const float* src; short* dst; int N, kg;
    if (blk < 392)      { src = dw;  dst = wpd; N = 512; kg = blk; }
    else if (blk < 456) { src = gk;  dst = wpg; N = 192; kg = blk - 392; }
    else if (blk < 488) { src = c1w; dst = wp1; N = 32;  kg = blk - 456; }
    else if (blk < 552) { src = c2w; dst = wp2; N = 64;  kg = blk - 488; }
    else if (blk < 624) { src = c3w; dst = wp3; N = 64;  kg = blk - 552; }
    else {
        // segment precompute: step dynamics depend only on dones/step0
        const int b = tid;
        if (b < BATCH) {
            int step = step0[b];
            int n = 0, start = 0;
            for (int t = 0; t < TSTEPS; ++t) {
                step += 1;
                const int reset = (dones[b * TSTEPS + t] == 1) || ((step % MEMN) == 0);
                if (reset) step = 0;
                if (reset || t == TSTEPS - 1) {
                    seg[b * TSTEPS + n] = start | ((t - start + 1) << 8) | (reset << 16);
                    n += 1;
                    start = t + 1;
                }
            }
            nseg[b] = n;
            out[OUT_FEATS + 1024 + b] = (float)step;
        }
        return;
    }

#pragma unroll
    for (int j = 0; j < 8; ++j)
        for (int n = tid; n < N; n += 256)
            lds[j * 513 + n] = src[(size_t)(kg * 8 + j) * N + n];
    __syncthreads();
    short* d = dst + (size_t)kg * N * 8;
    for (int t = tid; t < N * 8; t += 256) {
        int n = t >> 3, j = t & 7;
        d[t] = f2b(lds[j * 513 + n]);
    }
}

// ---------------- conv1 MFMA: in [n,84,84,4] fp32 -> out [n,400,32] bf16
__global__ __launch_bounds__(128) void conv1_mfma(
    const float* __restrict__ in, const short* __restrict__ wp,
    const float* __restrict__ bias, short* __restrict__ out)
{
    __shared__ short s[20 * 84 * 4];       // 26.9 KB bf16 slab
    const int tid = threadIdx.x;
    const int rg  = blockIdx.x;
    const int img = blockIdx.y;

    {
        const float4* src = reinterpret_cast<const float4*>(
            in + (size_t)img * 28224 + (size_t)rg * 5376);
        for (int i = tid; i < 1680; i += 128) {
            float4 v = src[i];
            short4v b; b.x = f2b(v.x); b.y = f2b(v.y); b.z = f2b(v.z); b.w = f2b(v.w);
            *reinterpret_cast<short4v*>(s + i * 4) = b;
        }
    }
    __syncthreads();

    const int w = tid >> 6, lane = tid & 63;
    const int row = lane & 15, g = lane >> 4;

    f32x4 acc[5];
#pragma unroll
    for (int i = 0; i < 5; ++i) acc[i] = (f32x4){0.f, 0.f, 0.f, 0.f};

    int soff[5];
#pragma unroll
    for (int mt = 0; mt < 5; ++mt) {
        int p = mt * 16 + row;             // 0..79
        int y = p / 20, x = p % 20;
        soff[mt] = ((y * 4) * 84 + x * 4 + g * 2) * 4;   // shorts
    }

    for (int ky = 0; ky < 8; ++ky) {
        const bf16x8 bfrag = *reinterpret_cast<const bf16x8*>(
            wp + ((size_t)(ky * 4 + g) * 32 + w * 16 + row) * 8);
#pragma unroll
        for (int mt = 0; mt < 5; ++mt) {
            const bf16x8 af = *reinterpret_cast<const bf16x8*>(s + soff[mt] + ky * 336);
            acc[mt] = __builtin_amdgcn_mfma_f32_16x16x32_bf16(af, bfrag, acc[mt], 0, 0, 0);
        }
    }

    const int n = w * 16 + row;
    const float bv = bias[n];
    short* ob = out + ((size_t)img * 400 + rg * 80) * 32;
#pragma unroll
    for (int mt = 0; mt < 5; ++mt)
#pragma unroll
        for (int r = 0; r < 4; ++r) {
            int p = mt * 16 + g * 4 + r;
            ob[p * 32 + n] = f2b(fmaxf(acc[mt][r] + bv, 0.f));
        }
}

// ---------------- fused conv2+conv3: in [n,400,32] bf16 -> out [n,3136] bf16
// conv2 result lives only in LDS (s3, conv3-swizzled); saves the c2o HBM trip.
__global__ __launch_bounds__(256) void conv23_mfma(
    const short* __restrict__ in, const short* __restrict__ wp2,
    const float* __restrict__ b2, const short* __restrict__ wp3,
    const float* __restrict__ b3, short* __restrict__ out)
{
    __shared__ short s2[400 * 32];         // 25.6 KB, conv2 input
    __shared__ short s3[81 * 64];          // 10.4 KB, conv2 output / conv3 input
    const int tid = threadIdx.x, img = blockIdx.x;

    // stage conv1-out, swizzle ^((q>>1)&7)<<4 (q = pixel, row = 64B)
    {
        const short* src = in + (size_t)img * 12800;
        for (int i = tid; i < 1600; i += 256) {
            bf16x8 v = *reinterpret_cast<const bf16x8*>(src + i * 8);
            int q = i >> 2;
            unsigned byte = (unsigned)(i * 16);
            byte ^= ((q >> 1) & 7) << 4;
            *reinterpret_cast<bf16x8*>(reinterpret_cast<char*>(s2) + byte) = v;
        }
    }
    __syncthreads();

    const int w = tid >> 6, lane = tid & 63;
    const int row = lane & 15, g = lane >> 4;

    // ---- conv2: M=81 (6 m-tiles), N=64, K=512
    {
        f32x4 acc[6];
#pragma unroll
        for (int i = 0; i < 6; ++i) acc[i] = (f32x4){0.f, 0.f, 0.f, 0.f};

        int qb[6];
#pragma unroll
        for (int mt = 0; mt < 6; ++mt) {
            int p = mt * 16 + row; if (p > 80) p = 80;
            int y = p / 9, x = p % 9;
            qb[mt] = y * 40 + x * 2;
        }

        for (int kt = 0; kt < 16; ++kt) {
            const int ky = kt >> 2, kx = kt & 3;
            const bf16x8 bfrag = *reinterpret_cast<const bf16x8*>(
                wp2 + ((size_t)(kt * 4 + g) * 64 + w * 16 + row) * 8);
            const int qoff = ky * 20 + kx;
#pragma unroll
            for (int mt = 0; mt < 6; ++mt) {
                int q = qb[mt] + qoff;
                unsigned byte = (unsigned)(q * 64 + g * 16);
                byte ^= ((q >> 1) & 7) << 4;
                const bf16x8 af = *reinterpret_cast<const bf16x8*>(
                    reinterpret_cast<const char*>(s2) + byte);
                acc[mt] = __builtin_amdgcn_mfma_f32_16x16x32_bf16(af, bfrag, acc[mt], 0, 0, 0);
            }
        }

        const int n = w * 16 + row;
        const float bv = b2[n];
#pragma unroll
        for (int mt = 0; mt < 6; ++mt)
#pragma unroll
            for (int r = 0; r < 4; ++r) {
                int p = mt * 16 + g * 4 + r;
                if (p < 81) {
                    unsigned byte = (unsigned)(p * 128 + n * 2);
                    byte ^= (p & 7) << 4;
                    *reinterpret_cast<short*>(reinterpret_cast<char*>(s3) + byte) =
                        f2b(fmaxf(acc[mt][r] + bv, 0.f));
                }
            }
    }
    __syncthreads();

    // ---- conv3: M=49 (4 m-tiles), N=64, K=576, reads s3 with ^((q&7)<<4)
    {
        f32x4 acc[4];
#pragma unroll
        for (int i = 0; i < 4; ++i) acc[i] = (f32x4){0.f, 0.f, 0.f, 0.f};

        int qb[4];
#pragma unroll
        for (int mt = 0; mt < 4; ++mt) {
            int p = mt * 16 + row; if (p > 48) p = 48;
            int y = p / 7, x = p % 7;
            qb[mt] = y * 9 + x;
        }

        for (int kt = 0; kt < 18; ++kt) {
            const int kxy = kt >> 1;
            const int ky = kxy / 3, kx = kxy - ky * 3;
            const int coff = (kt & 1) * 64 + g * 16;
            const bf16x8 bfrag = *reinterpret_cast<const bf16x8*>(
                wp3 + ((size_t)(kt * 4 + g) * 64 + w * 16 + row) * 8);
            const int qoff = ky * 9 + kx;
#pragma unroll
            for (int mt = 0; mt < 4; ++mt) {
                int q = qb[mt] + qoff;
                unsigned byte = (unsigned)(q * 128 + coff);
                byte ^= (q & 7) << 4;
                const bf16x8 af = *reinterpret_cast<const bf16x8*>(
                    reinterpret_cast<const char*>(s3) + byte);
                acc[mt] = __builtin_amdgcn_mfma_f32_16x16x32_bf16(af, bfrag, acc[mt], 0, 0, 0);
            }
        }

        const int n = w * 16 + row;
        const float bv = b3[n];
        short* ob = out + (size_t)img * 3136;
#pragma unroll
        for (int mt = 0; mt < 4; ++mt)
#pragma unroll
            for (int r = 0; r < 4; ++r) {
                int p = mt * 16 + g * 4 + r;
                if (p < 49) ob[p * 64 + n] = f2b(fmaxf(acc[mt][r] + bv, 0.f));
            }
    }
}

// ---------------- dense MFMA: feats = relu(A[2048,3136] @ W + b) -> out fp32
__global__ __launch_bounds__(512) void dense_mfma(
    const short* __restrict__ A, const short* __restrict__ wp,
    const float* __restrict__ bias, float* __restrict__ outp)
{
    const int tid = threadIdx.x;
    const int w = tid >> 6, lane = tid & 63;
    const int row = lane & 15, g = lane >> 4;
    const int bm0 = blockIdx.x * 64, bn0 = blockIdx.y * 64;
    const int nt = w & 3, mtb = (w >> 2) * 2;

    f32x4 acc0 = (f32x4){0.f, 0.f, 0.f, 0.f};
    f32x4 acc1 = (f32x4){0.f, 0.f, 0.f, 0.f};

    const short* a0 = A + (size_t)(bm0 + mtb * 16 + row) * FLAT + g * 8;
    const short* a1 = a0 + 16 * FLAT;
    const short* bp = wp + ((size_t)g * FEAT + bn0 + nt * 16 + row) * 8;

    for (int kt = 0; kt < 98; ++kt) {
        const bf16x8 b  = *reinterpret_cast<const bf16x8*>(bp + (size_t)kt * 4 * FEAT * 8);
        const bf16x8 x0 = *reinterpret_cast<const bf16x8*>(a0 + kt * 32);
        const bf16x8 x1 = *reinterpret_cast<const bf16x8*>(a1 + kt * 32);
        acc0 = __builtin_amdgcn_mfma_f32_16x16x32_bf16(x0, b, acc0, 0, 0, 0);
        acc1 = __builtin_amdgcn_mfma_f32_16x16x32_bf16(x1, b, acc1, 0, 0, 0);
    }

    const int n = bn0 + nt * 16 + row;
    const float bv = bias[n];
#pragma unroll
    for (int r = 0; r < 4; ++r) {
        int m0 = bm0 + mtb * 16 + g * 4 + r;
        outp[(size_t)m0 * OUTROW + n] = fmaxf(acc0[r] + bv, 0.f);
        int m1 = m0 + 16;
        outp[(size_t)m1 * OUTROW + n] = fmaxf(acc1[r] + bv, 0.f);
    }
}

// ---------------- mx MFMA: mx[2048,192] = feats(out fp32, stride 576) @ gru_k + bi
__global__ __launch_bounds__(512) void mx_mfma(
    const float* __restrict__ A, const short* __restrict__ wp,
    const float* __restrict__ gb, float* __restrict__ mx)
{
    const int tid = threadIdx.x;
    const int w = tid >> 6, lane = tid & 63;
    const int row = lane & 15, g = lane >> 4;
    const int bm0 = blockIdx.x * 64, bn0 = blockIdx.y * 64;
    const int nt = w & 3, mtb = (w >> 2) * 2;

    f32x4 acc0 = (f32x4){0.f, 0.f, 0.f, 0.f};
    f32x4 acc1 = (f32x4){0.f, 0.f, 0.f, 0.f};

    const float* a0 = A + (size_t)(bm0 + mtb * 16 + row) * OUTROW + g * 8;
    const float* a1 = a0 + (size_t)16 * OUTROW;
    const short* bp = wp + ((size_t)g * 192 + bn0 + nt * 16 + row) * 8;

    for (int kt = 0; kt < 16; ++kt) {
        const bf16x8 b = *reinterpret_cast<const bf16x8*>(bp + (size_t)kt * 4 * 192 * 8);
        const float4 u0 = *reinterpret_cast<const float4*>(a0 + kt * 32);
        const float4 u1 = *reinterpret_cast<const float4*>(a0 + kt * 32 + 4);
        const float4 v0 = *reinterpret_cast<const float4*>(a1 + kt * 32);
        const float4 v1 = *reinterpret_cast<const float4*>(a1 + kt * 32 + 4);
        bf16x8 x0, x1;
        x0[0] = f2b(u0.x); x0[1] = f2b(u0.y); x0[2] = f2b(u0.z); x0[3] = f2b(u0.w);
        x0[4] = f2b(u1.x); x0[5] = f2b(u1.y); x0[6] = f2b(u1.z); x0[7] = f2b(u1.w);
        x1[0] = f2b(v0.x); x1[1] = f2b(v0.y); x1[2] = f2b(v0.z); x1[3] = f2b(v0.w);
        x1[4] = f2b(v1.x); x1[5] = f2b(v1.y); x1[6] = f2b(v1.z); x1[7] = f2b(v1.w);
        acc0 = __builtin_amdgcn_mfma_f32_16x16x32_bf16(x0, b, acc0, 0, 0, 0);
        acc1 = __builtin_amdgcn_mfma_f32_16x16x32_bf16(x1, b, acc1, 0, 0, 0);
    }

    const int n = bn0 + nt * 16 + row;
    const float bv = gb[n];                 // bi row
#pragma unroll
    for (int r = 0; r < 4; ++r) {
        int m0 = bm0 + mtb * 16 + g * 4 + r;
        mx[(size_t)m0 * 192 + n] = acc0[r] + bv;
        int m1 = m0 + 16;
        mx[(size_t)m1 * 192 + n] = acc1[r] + bv;
    }
}

// ---------------- GRU segments: one wave per segment (<=16 steps, no resets inside)
__global__ __launch_bounds__(64) void gru_seg_kernel(
    const float* __restrict__ mx,     // [2048,192]
    const float* __restrict__ rk,     // [64,192]
    const float* __restrict__ gb,     // [2,192]; br = gb + 192
    const float* __restrict__ state0, // [16,64]
    const int*   __restrict__ seg, const int* __restrict__ nseg,
    float* __restrict__ out)
{
    const int b = blockIdx.x >> 7;
    const int i = blockIdx.x & 127;
    if (i >= nseg[b]) return;
    const int e = seg[b * TSTEPS + i];
    const int start = e & 255;
    const int len   = (e >> 8) & 255;
    const int rend  = (e >> 16) & 1;

    const int u = threadIdx.x;
    float h = (start == 0) ? state0[b * 64 + u] : 0.f;
    const float brz = gb[192 + u];
    const float brr = gb[192 + 64 + u];
    const float brh = gb[192 + 128 + u];

    for (int k = 0; k < len; ++k) {
        const int bt = b * TSTEPS + start + k;
        float az = 0.f, ar = 0.f, ah = 0.f;
#pragma unroll 16
        for (int j = 0; j < 64; ++j) {
            const float hj = __shfl(h, j);
            az = fmaf(hj, rk[j * 192 + u], az);
            ar = fmaf(hj, rk[j * 192 + 64 + u], ar);
            ah = fmaf(hj, rk[j * 192 + 128 + u], ah);
        }
        const float xz = mx[(size_t)bt * 192 + u];
        const float xr = mx[(size_t)bt * 192 + 64 + u];
        const float xh = mx[(size_t)bt * 192 + 128 + u];
        const float z = 1.f / (1.f + __expf(-(xz + az + brz)));
        const float r = 1.f / (1.f + __expf(-(xr + ar + brr)));
        const float hh = tanhf(xh + r * (ah + brh));
        const float hn = z * h + (1.f - z) * hh;

        out[(size_t)bt * OUTROW + 512 + u] = hn;
        h = hn;
    }

    if (start + len == TSTEPS) {
        out[OUT_FEATS + b * 64 + u] = rend ? 0.f : h;
    }
}

extern "C" void kernel_launch(void* const* d_in, const int* in_sizes, int n_in,
                              void* d_out, int out_size, void* d_ws, size_t ws_size,
                              hipStream_t stream) {
    const float* inputs = (const float*)d_in[0];
    const int*   dones  = (const int*)d_in[1];
    const float* state0 = (const float*)d_in[2];
    const int*   step0  = (const int*)d_in[3];
    const float* c1w = (const float*)d_in[4];
    const float* c1b = (const float*)d_in[5];
    const float* c2w = (const float*)d_in[6];
    const float* c2b = (const float*)d_in[7];
    const float* c3w = (const float*)d_in[8];
    const float* c3b = (const float*)d_in[9];
    const float* dw  = (const float*)d_in[10];
    const float* db  = (const float*)d_in[11];
    const float* gk  = (const float*)d_in[12];
    const float* grk = (const float*)d_in[13];
    const float* gbv = (const float*)d_in[14];

    float* out = (float*)d_out;

    // workspace carve (256 B aligned). Total ~70 MB.
    char* p = (char*)d_ws;
    auto alloc = [&](size_t bytes) {
        char* r = p; p += (bytes + 255) & ~(size_t)255; return r;
    };
    short* wp1 = (short*)alloc((size_t)8192 * 2);
    short* wp2 = (short*)alloc((size_t)32768 * 2);
    short* wp3 = (short*)alloc((size_t)36864 * 2);
    short* wpd = (short*)alloc((size_t)FLAT * FEAT * 2);
    short* wpg = (short*)alloc((size_t)FEAT * 192 * 2);
    short* c1o = (short*)alloc((size_t)NIMG * 12800 * 2);
    short* c3o = (short*)alloc((size_t)NIMG * FLAT * 2);
    float* mxb = (float*)alloc((size_t)NIMG * 192 * 4);
    int*   segb = (int*)alloc((size_t)BATCH * TSTEPS * 4);
    int*   nsegb = (int*)alloc((size_t)BATCH * 4);

    // pack all weights + seg precompute, one launch
    megapack<<<625, 256, 0, stream>>>(dw, gk, c1w, c2w, c3w,
                                      wpd, wpg, wp1, wp2, wp3,
                                      dones, step0, segb, nsegb, out);

    dim3 g1(5, NIMG);
    conv1_mfma<<<g1, 128, 0, stream>>>(inputs, wp1, c1b, c1o);
    conv23_mfma<<<NIMG, 256, 0, stream>>>(c1o, wp2, c2b, wp3, c3b, c3o);

    dim3 gd(NIMG / 64, FEAT / 64);
    dense_mfma<<<gd, 512, 0, stream>>>(c3o, wpd, db, out);

    dim3 gm(NIMG / 64, 192 / 64);
    mx_mfma<<<gm, 512, 0, stream>>>(out, wpg, gbv, mxb);

    gru_seg_kernel<<<BATCH * TSTEPS, 64, 0, stream>>>(
        mxb, grk, gbv, state0, segb, nsegb, out);
}

// Round 7
// 208.528 us; speedup vs baseline: 13.7982x; 1.0713x over previous
//
#include <hip/hip_runtime.h>
#include <math.h>

#define BATCH 16
#define TSTEPS 128
#define UNITS 64
#define FEAT 512
#define FLAT 3136
#define OUTROW 576           // 512 + 64
#define OUT_FEATS (BATCH * TSTEPS * OUTROW)   // 1179648
#define MEMN 16
#define NIMG 2048

typedef short bf16x8 __attribute__((ext_vector_type(8)));
typedef short short4v __attribute__((ext_vector_type(4)));
typedef float f32x4 __attribute__((ext_vector_type(4)));

__device__ __forceinline__ short f2b(float f) {
    unsigned u = __float_as_uint(f);
    unsigned r = (u + 0x7FFFu + ((u >> 16) & 1u)) >> 16;
    return (short)r;
}

// ---------------- mega-pack: all weight matrices fp32 [K][N] -> bf16 [K/8][N][8]
// (coalesced via LDS transpose) + seg precompute as the last block.
__global__ __launch_bounds__(256) void megapack(
    const float* __restrict__ dw, const float* __restrict__ gk,
    const float* __restrict__ c1w, const float* __restrict__ c2w,
    const float* __restrict__ c3w,
    short* __restrict__ wpd, short* __restrict__ wpg, short* __restrict__ wp1,
    short* __restrict__ wp2, short* __restrict__ wp3,
    const int* __restrict__ dones, const int* __restrict__ step0,
    int* __restrict__ seg, int* __restrict__ nseg, float* __restrict__ out)
{
    __shared__ float lds[8 * 513];         // 16.4 KB, pad 513 -> conflict-free
    const int blk = blockIdx.x;
    const int tid = threadIdx.x;

    const float* src; short* dst; int N, kg;
    if (blk < 392)      { src = dw;  dst = wpd; N = 512; kg = blk; }
    else if (blk < 456) { src = gk;  dst = wpg; N = 192; kg = blk - 392; }
    else if (blk < 488) { src = c1w; dst = wp1; N = 32;  kg = blk - 456; }
    else if (blk < 552) { src = c2w; dst = wp2; N = 64;  kg = blk - 488; }
    else if (blk < 624) { src = c3w; dst = wp3; N = 64;  kg = blk - 552; }
    else {
        // segment precompute: step dynamics depend only on dones/step0
        const int b = tid;
        if (b < BATCH) {
            int step = step0[b];
            int n = 0, start = 0;
            for (int t = 0; t < TSTEPS; ++t) {
                step += 1;
                const int reset = (dones[b * TSTEPS + t] == 1) || ((step % MEMN) == 0);
                if (reset) step = 0;
                if (reset || t == TSTEPS - 1) {
                    seg[b * TSTEPS + n] = start | ((t - start + 1) << 8) | (reset << 16);
                    n += 1;
                    start = t + 1;
                }
            }
            nseg[b] = n;
            out[OUT_FEATS + 1024 + b] = (float)step;
        }
        return;
    }

#pragma unroll
    for (int j = 0; j < 8; ++j)
        for (int n = tid; n < N; n += 256)
            lds[j * 513 + n] = src[(size_t)(kg * 8 + j) * N + n];
    __syncthreads();
    short* d = dst + (size_t)kg * N * 8;
    for (int t = tid; t < N * 8; t += 256) {
        int n = t >> 3, j = t & 7;
        d[t] = f2b(lds[j * 513 + n]);
    }
}

// ---------------- fused conv tower: in [n,84,84,4] fp32 -> out [n,3136] bf16
// One block per image, 256 thr = 4 waves, 49 KB LDS -> 3 blocks/CU.
// conv1: 3 staging phases (rows 0-35 / 32-67 / 64-83), 25 full m-tiles,
// writes s2 with conv2 swizzle. conv2 -> s3 (aliases dead s1). conv3 -> global.
__global__ __launch_bounds__(256) void convtower_mfma(
    const float* __restrict__ in,
    const short* __restrict__ wp1, const float* __restrict__ b1,
    const short* __restrict__ wp2, const float* __restrict__ b2,
    const short* __restrict__ wp3, const float* __restrict__ b3,
    short* __restrict__ out)
{
    __shared__ short smem[25088];      // 49 KB
    short* s1 = smem;                  // [0, 12288) input slab (36 rows max)
    short* s2 = smem + 12288;          // [12288, 25088) conv1-out, conv2-swizzled
    short* s3 = smem;                  // alias: conv2-out (s1 dead by then)

    const int tid = threadIdx.x, img = blockIdx.x;
    const int w = tid >> 6, lane = tid & 63;
    const int row = lane & 15, g = lane >> 4;
    const int wn = w & 1, wm = w >> 1;     // conv1: n-tile, m-parity

    const float* ibase = in + (size_t)img * 28224;

    // conv1 B-frags hoisted (8 ky), n = wn*16+row
    bf16x8 bf1[8];
#pragma unroll
    for (int ky = 0; ky < 8; ++ky)
        bf1[ky] = *reinterpret_cast<const bf16x8*>(
            wp1 + ((size_t)(ky * 4 + g) * 32 + wn * 16 + row) * 8);
    const float bv1 = b1[wn * 16 + row];

    const int pbase[3] = {0, 32, 64};      // input row base per phase
    const int prows[3] = {36, 36, 20};     // rows staged
    const int pmt0[3]  = {0, 10, 20};      // first m-tile
    const int pnmt[3]  = {10, 10, 5};      // m-tiles in phase

    for (int ph = 0; ph < 3; ++ph) {
        if (ph) __syncthreads();           // prior phase done reading s1
        {
            const float4* src = reinterpret_cast<const float4*>(ibase + pbase[ph] * 336);
            const int nvec = prows[ph] * 84;
            for (int i = tid; i < nvec; i += 256) {
                float4 v = src[i];
                short4v b4; b4.x = f2b(v.x); b4.y = f2b(v.y); b4.z = f2b(v.z); b4.w = f2b(v.w);
                *reinterpret_cast<short4v*>(s1 + i * 4) = b4;
            }
        }
        __syncthreads();

        for (int mt = pmt0[ph] + wm; mt < pmt0[ph] + pnmt[ph]; mt += 2) {
            const int p = mt * 16 + row;       // pixel 0..399, all tiles full
            const int y = p / 20, x = p % 20;
            const int lr0 = 4 * y - pbase[ph];
            const short* ap = s1 + (lr0 * 84 + 4 * x + g * 2) * 4;
            f32x4 acc = (f32x4){0.f, 0.f, 0.f, 0.f};
#pragma unroll
            for (int ky = 0; ky < 8; ++ky) {
                const bf16x8 af = *reinterpret_cast<const bf16x8*>(ap + ky * 336);
                acc = __builtin_amdgcn_mfma_f32_16x16x32_bf16(af, bf1[ky], acc, 0, 0, 0);
            }
            const int n = wn * 16 + row;
#pragma unroll
            for (int r = 0; r < 4; ++r) {
                int po = mt * 16 + g * 4 + r;
                unsigned byte = (unsigned)(po * 64 + n * 2);
                byte ^= ((po >> 1) & 7) << 4;
                *reinterpret_cast<short*>(reinterpret_cast<char*>(s2) + byte) =
                    f2b(fmaxf(acc[r] + bv1, 0.f));
            }
        }
    }
    __syncthreads();

    // ---- conv2: M=81 (6 m-tiles), N=64, K=512; reads s2, writes s3 (swizzled)
    {
        f32x4 acc[6];
#pragma unroll
        for (int i = 0; i < 6; ++i) acc[i] = (f32x4){0.f, 0.f, 0.f, 0.f};

        int qb[6];
#pragma unroll
        for (int mt = 0; mt < 6; ++mt) {
            int p = mt * 16 + row; if (p > 80) p = 80;
            int y = p / 9, x = p % 9;
            qb[mt] = y * 40 + x * 2;
        }

        for (int kt = 0; kt < 16; ++kt) {
            const int ky = kt >> 2, kx = kt & 3;
            const bf16x8 bfrag = *reinterpret_cast<const bf16x8*>(
                wp2 + ((size_t)(kt * 4 + g) * 64 + w * 16 + row) * 8);
            const int qoff = ky * 20 + kx;
#pragma unroll
            for (int mt = 0; mt < 6; ++mt) {
                int q = qb[mt] + qoff;
                unsigned byte = (unsigned)(q * 64 + g * 16);
                byte ^= ((q >> 1) & 7) << 4;
                const bf16x8 af = *reinterpret_cast<const bf16x8*>(
                    reinterpret_cast<const char*>(s2) + byte);
                acc[mt] = __builtin_amdgcn_mfma_f32_16x16x32_bf16(af, bfrag, acc[mt], 0, 0, 0);
            }
        }

        const int n = w * 16 + row;
        const float bv = b2[n];
#pragma unroll
        for (int mt = 0; mt < 6; ++mt)
#pragma unroll
            for (int r = 0; r < 4; ++r) {
                int p = mt * 16 + g * 4 + r;
                if (p < 81) {
                    unsigned byte = (unsigned)(p * 128 + n * 2);
                    byte ^= (p & 7) << 4;
                    *reinterpret_cast<short*>(reinterpret_cast<char*>(s3) + byte) =
                        f2b(fmaxf(acc[mt][r] + bv, 0.f));
                }
            }
    }
    __syncthreads();

    // ---- conv3: M=49 (4 m-tiles), N=64, K=576; reads s3, writes global
    {
        f32x4 acc[4];
#pragma unroll
        for (int i = 0; i < 4; ++i) acc[i] = (f32x4){0.f, 0.f, 0.f, 0.f};

        int qb[4];
#pragma unroll
        for (int mt = 0; mt < 4; ++mt) {
            int p = mt * 16 + row; if (p > 48) p = 48;
            int y = p / 7, x = p % 7;
            qb[mt] = y * 9 + x;
        }

        for (int kt = 0; kt < 18; ++kt) {
            const int kxy = kt >> 1;
            const int ky = kxy / 3, kx = kxy - ky * 3;
            const int coff = (kt & 1) * 64 + g * 16;
            const bf16x8 bfrag = *reinterpret_cast<const bf16x8*>(
                wp3 + ((size_t)(kt * 4 + g) * 64 + w * 16 + row) * 8);
            const int qoff = ky * 9 + kx;
#pragma unroll
            for (int mt = 0; mt < 4; ++mt) {
                int q = qb[mt] + qoff;
                unsigned byte = (unsigned)(q * 128 + coff);
                byte ^= (q & 7) << 4;
                const bf16x8 af = *reinterpret_cast<const bf16x8*>(
                    reinterpret_cast<const char*>(s3) + byte);
                acc[mt] = __builtin_amdgcn_mfma_f32_16x16x32_bf16(af, bfrag, acc[mt], 0, 0, 0);
            }
        }

        const int n = w * 16 + row;
        const float bv = b3[n];
        short* ob = out + (size_t)img * 3136;
#pragma unroll
        for (int mt = 0; mt < 4; ++mt)
#pragma unroll
            for (int r = 0; r < 4; ++r) {
                int p = mt * 16 + g * 4 + r;
                if (p < 49) ob[p * 64 + n] = f2b(fmaxf(acc[mt][r] + bv, 0.f));
            }
    }
}

// ---------------- dense MFMA: feats = relu(A[2048,3136] @ W + b) -> out fp32
__global__ __launch_bounds__(512) void dense_mfma(
    const short* __restrict__ A, const short* __restrict__ wp,
    const float* __restrict__ bias, float* __restrict__ outp)
{
    const int tid = threadIdx.x;
    const int w = tid >> 6, lane = tid & 63;
    const int row = lane & 15, g = lane >> 4;
    const int bm0 = blockIdx.x * 64, bn0 = blockIdx.y * 64;
    const int nt = w & 3, mtb = (w >> 2) * 2;

    f32x4 acc0 = (f32x4){0.f, 0.f, 0.f, 0.f};
    f32x4 acc1 = (f32x4){0.f, 0.f, 0.f, 0.f};

    const short* a0 = A + (size_t)(bm0 + mtb * 16 + row) * FLAT + g * 8;
    const short* a1 = a0 + 16 * FLAT;
    const short* bp = wp + ((size_t)g * FEAT + bn0 + nt * 16 + row) * 8;

    for (int kt = 0; kt < 98; ++kt) {
        const bf16x8 b  = *reinterpret_cast<const bf16x8*>(bp + (size_t)kt * 4 * FEAT * 8);
        const bf16x8 x0 = *reinterpret_cast<const bf16x8*>(a0 + kt * 32);
        const bf16x8 x1 = *reinterpret_cast<const bf16x8*>(a1 + kt * 32);
        acc0 = __builtin_amdgcn_mfma_f32_16x16x32_bf16(x0, b, acc0, 0, 0, 0);
        acc1 = __builtin_amdgcn_mfma_f32_16x16x32_bf16(x1, b, acc1, 0, 0, 0);
    }

    const int n = bn0 + nt * 16 + row;
    const float bv = bias[n];
#pragma unroll
    for (int r = 0; r < 4; ++r) {
        int m0 = bm0 + mtb * 16 + g * 4 + r;
        outp[(size_t)m0 * OUTROW + n] = fmaxf(acc0[r] + bv, 0.f);
        int m1 = m0 + 16;
        outp[(size_t)m1 * OUTROW + n] = fmaxf(acc1[r] + bv, 0.f);
    }
}

// ---------------- mx MFMA: mx[2048,192] = feats(out fp32, stride 576) @ gru_k + bi
__global__ __launch_bounds__(512) void mx_mfma(
    const float* __restrict__ A, const short* __restrict__ wp,
    const float* __restrict__ gb, float* __restrict__ mx)
{
    const int tid = threadIdx.x;
    const int w = tid >> 6, lane = tid & 63;
    const int row = lane & 15, g = lane >> 4;
    const int bm0 = blockIdx.x * 64, bn0 = blockIdx.y * 64;
    const int nt = w & 3, mtb = (w >> 2) * 2;

    f32x4 acc0 = (f32x4){0.f, 0.f, 0.f, 0.f};
    f32x4 acc1 = (f32x4){0.f, 0.f, 0.f, 0.f};

    const float* a0 = A + (size_t)(bm0 + mtb * 16 + row) * OUTROW + g * 8;
    const float* a1 = a0 + (size_t)16 * OUTROW;
    const short* bp = wp + ((size_t)g * 192 + bn0 + nt * 16 + row) * 8;

    for (int kt = 0; kt < 16; ++kt) {
        const bf16x8 b = *reinterpret_cast<const bf16x8*>(bp + (size_t)kt * 4 * 192 * 8);
        const float4 u0 = *reinterpret_cast<const float4*>(a0 + kt * 32);
        const float4 u1 = *reinterpret_cast<const float4*>(a0 + kt * 32 + 4);
        const float4 v0 = *reinterpret_cast<const float4*>(a1 + kt * 32);
        const float4 v1 = *reinterpret_cast<const float4*>(a1 + kt * 32 + 4);
        bf16x8 x0, x1;
        x0[0] = f2b(u0.x); x0[1] = f2b(u0.y); x0[2] = f2b(u0.z); x0[3] = f2b(u0.w);
        x0[4] = f2b(u1.x); x0[5] = f2b(u1.y); x0[6] = f2b(u1.z); x0[7] = f2b(u1.w);
        x1[0] = f2b(v0.x); x1[1] = f2b(v0.y); x1[2] = f2b(v0.z); x1[3] = f2b(v0.w);
        x1[4] = f2b(v1.x); x1[5] = f2b(v1.y); x1[6] = f2b(v1.z); x1[7] = f2b(v1.w);
        acc0 = __builtin_amdgcn_mfma_f32_16x16x32_bf16(x0, b, acc0, 0, 0, 0);
        acc1 = __builtin_amdgcn_mfma_f32_16x16x32_bf16(x1, b, acc1, 0, 0, 0);
    }

    const int n = bn0 + nt * 16 + row;
    const float bv = gb[n];                 // bi row
#pragma unroll
    for (int r = 0; r < 4; ++r) {
        int m0 = bm0 + mtb * 16 + g * 4 + r;
        mx[(size_t)m0 * 192 + n] = acc0[r] + bv;
        int m1 = m0 + 16;
        mx[(size_t)m1 * 192 + n] = acc1[r] + bv;
    }
}

// ---------------- GRU segments: one wave per segment (<=16 steps, no resets inside)
__global__ __launch_bounds__(64) void gru_seg_kernel(
    const float* __restrict__ mx,     // [2048,192]
    const float* __restrict__ rk,     // [64,192]
    const float* __restrict__ gb,     // [2,192]; br = gb + 192
    const float* __restrict__ state0, // [16,64]
    const int*   __restrict__ seg, const int* __restrict__ nseg,
    float* __restrict__ out)
{
    const int b = blockIdx.x >> 7;
    const int i = blockIdx.x & 127;
    if (i >= nseg[b]) return;
    const int e = seg[b * TSTEPS + i];
    const int start = e & 255;
    const int len   = (e >> 8) & 255;
    const int rend  = (e >> 16) & 1;

    const int u = threadIdx.x;
    float h = (start == 0) ? state0[b * 64 + u] : 0.f;
    const float brz = gb[192 + u];
    const float brr = gb[192 + 64 + u];
    const float brh = gb[192 + 128 + u];

    for (int k = 0; k < len; ++k) {
        const int bt = b * TSTEPS + start + k;
        float az = 0.f, ar = 0.f, ah = 0.f;
#pragma unroll 16
        for (int j = 0; j < 64; ++j) {
            const float hj = __shfl(h, j);
            az = fmaf(hj, rk[j * 192 + u], az);
            ar = fmaf(hj, rk[j * 192 + 64 + u], ar);
            ah = fmaf(hj, rk[j * 192 + 128 + u], ah);
        }
        const float xz = mx[(size_t)bt * 192 + u];
        const float xr = mx[(size_t)bt * 192 + 64 + u];
        const float xh = mx[(size_t)bt * 192 + 128 + u];
        const float z = 1.f / (1.f + __expf(-(xz + az + brz)));
        const float r = 1.f / (1.f + __expf(-(xr + ar + brr)));
        const float hh = tanhf(xh + r * (ah + brh));
        const float hn = z * h + (1.f - z) * hh;

        out[(size_t)bt * OUTROW + 512 + u] = hn;
        h = hn;
    }

    if (start + len == TSTEPS) {
        out[OUT_FEATS + b * 64 + u] = rend ? 0.f : h;
    }
}

extern "C" void kernel_launch(void* const* d_in, const int* in_sizes, int n_in,
                              void* d_out, int out_size, void* d_ws, size_t ws_size,
                              hipStream_t stream) {
    const float* inputs = (const float*)d_in[0];
    const int*   dones  = (const int*)d_in[1];
    const float* state0 = (const float*)d_in[2];
    const int*   step0  = (const int*)d_in[3];
    const float* c1w = (const float*)d_in[4];
    const float* c1b = (const float*)d_in[5];
    const float* c2w = (const float*)d_in[6];
    const float* c2b = (const float*)d_in[7];
    const float* c3w = (const float*)d_in[8];
    const float* c3b = (const float*)d_in[9];
    const float* dw  = (const float*)d_in[10];
    const float* db  = (const float*)d_in[11];
    const float* gk  = (const float*)d_in[12];
    const float* grk = (const float*)d_in[13];
    const float* gbv = (const float*)d_in[14];

    float* out = (float*)d_out;

    // workspace carve (256 B aligned). Total ~18 MB.
    char* p = (char*)d_ws;
    auto alloc = [&](size_t bytes) {
        char* r = p; p += (bytes + 255) & ~(size_t)255; return r;
    };
    short* wp1 = (short*)alloc((size_t)8192 * 2);
    short* wp2 = (short*)alloc((size_t)32768 * 2);
    short* wp3 = (short*)alloc((size_t)36864 * 2);
    short* wpd = (short*)alloc((size_t)FLAT * FEAT * 2);
    short* wpg = (short*)alloc((size_t)FEAT * 192 * 2);
    short* c3o = (short*)alloc((size_t)NIMG * FLAT * 2);
    float* mxb = (float*)alloc((size_t)NIMG * 192 * 4);
    int*   segb = (int*)alloc((size_t)BATCH * TSTEPS * 4);
    int*   nsegb = (int*)alloc((size_t)BATCH * 4);

    // pack all weights + seg precompute, one launch
    megapack<<<625, 256, 0, stream>>>(dw, gk, c1w, c2w, c3w,
                                      wpd, wpg, wp1, wp2, wp3,
                                      dones, step0, segb, nsegb, out);

    convtower_mfma<<<NIMG, 256, 0, stream>>>(inputs, wp1, c1b, wp2, c2b, wp3, c3b, c3o);

    dim3 gd(NIMG / 64, FEAT / 64);
    dense_mfma<<<gd, 512, 0, stream>>>(c3o, wpd, db, out);

    dim3 gm(NIMG / 64, 192 / 64);
    mx_mfma<<<gm, 512, 0, stream>>>(out, wpg, gbv, mxb);

    gru_seg_kernel<<<BATCH * TSTEPS, 64, 0, stream>>>(
        mxb, grk, gbv, state0, segb, nsegb, out);
}